// Round 1
// baseline (235.678 us; speedup 1.0000x reference)
//
#include <hip/hip_runtime.h>
#include <hip/hip_cooperative_groups.h>

namespace cg = cooperative_groups;

#define NPAIR 8192   // B*NCG

// ===================== config-deduplicated path =====================
// Node layer-1 output depends only on (c, i, f_s0, op_s0, f_s1, op_s1):
// 5292 real configs + 4 init pseudo-rows = 5296. Phase 1 builds
// tab[cfg] = relu(y1_cfg) @ W2; phase 2 is a pure gather/aggregate.
// R14 forensics: 512-thread kernels with indexed acc[]/yv[] register arrays
// get VGPR-capped at 128 and the arrays land in scratch. Fix: 256 threads,
// 4 waves x 4 configs, matvec with SCALAR accumulators (VGPR 56-68, no spill).
// R15: fuse the two launches into ONE cooperative kernel with grid.sync();
// the two-dispatch graph paid ~70us of launch/gap overhead on ~25us of body.
#define NCFG_REAL 5292
#define NCFG      5296
#define CPER      2646
#define WS_AT2F   0         // at2 table [7][128] (row 0 zeroed)
#define WS_TAB    1024      // tab [NCFG][128]
#define WS_NEED   ((size_t)(1024 + NCFG * 128) * 4)

#define COMP4(v, j) ((j) == 0 ? (v).x : (j) == 1 ? (v).y : (j) == 2 ? (v).z : (v).w)

__device__ __forceinline__ float sigmoidf_(float x) {
  return 1.0f / (1.0f + __expf(-x));
}

// ---------------------------------------------------------------------------
// Fused cooperative kernel: 512 blocks x 256 threads.
// Phase 1 (blocks 0..330): 16 configs each (331*16 = 5296 exact) -> tab in ws.
// grid.sync() with device fence (per-XCD L2s are not coherent).
// Phase 2 (all 512 blocks): 16 pairs each (512*16 = 8192 exact).
// Co-residency: 39KB LDS -> 4 blocks/CU capacity; launch_bounds(256,2)
// guarantees the register allocation for >=2 blocks/CU. 512 <= 2*256. Safe.
// ---------------------------------------------------------------------------
__global__ __launch_bounds__(256, 2) void fused_kernel(
    const float* __restrict__ init_emb, const float* __restrict__ other_emb,
    const float* __restrict__ op_embs,  const float* __restrict__ Wx,
    const float* __restrict__ bx,       const float* __restrict__ W1,
    const float* __restrict__ Wa1,      const float* __restrict__ ba1,
    const float* __restrict__ W2,       const float* __restrict__ Wa2,
    const float* __restrict__ ba2,      const int* __restrict__ archs,
    float* __restrict__ ws,             float* __restrict__ out)
{
  __shared__ __align__(16) float wsh[6144];   // weight staging; later y1 [4][4][128]; phase2: archsh
  __shared__ __align__(16) float s1sh[1536];  // support1 [2][6][128]
  __shared__ __align__(16) float at1sh[896];  // [7][128] row0=0
  __shared__ __align__(16) float at2sh[896];  // embeddings scratch, then at2
  __shared__ __align__(16) float y0[576];     // y0, then op_embs scratch
  const int t = threadIdx.x;

  if (blockIdx.x < 331) {
    // ---- step 1: stage Wx (576 float4) -> wsh; embeddings (84 f4) -> at2sh --
    for (int i = t; i < 576; i += 256) ((float4*)wsh)[i] = ((const float4*)Wx)[i];
    if (t < 48)       ((float4*)at2sh)[t] = ((const float4*)init_emb)[t];
    else if (t < 72)  ((float4*)at2sh)[t] = ((const float4*)other_emb)[t - 48];
    else if (t < 84)  ((float4*)at2sh)[t] = ((const float4*)bx)[t - 72];
    __syncthreads();

    // ---- step 2: y0[c][i][h] = node @ Wx + bx (all LDS operands) ----
    for (int idx = t; idx < 576; idx += 256) {
      int c = idx / 288, i = (idx / 48) % 6, h = idx % 48;
      const float* nptr = (i < 2) ? (at2sh + (c * 2 + i) * 48)
                                  : (at2sh + 192 + c * 48);
      float acc = at2sh[288 + h];
      for (int d = 0; d < 48; ++d) acc += nptr[d] * wsh[d * 48 + h];
      y0[idx] = acc;
    }
    __syncthreads();

    // ---- step 3: stage W1 (1536 float4) -> wsh; s1 = y0 @ W1 ----
    for (int i = t; i < 1536; i += 256) ((float4*)wsh)[i] = ((const float4*)W1)[i];
    __syncthreads();
    for (int idx = t; idx < 1536; idx += 256) {
      int ci = idx >> 7, o = idx & 127;
      const float* yp = y0 + ci * 48;
      float acc = 0.f;
      for (int h = 0; h < 48; ++h) acc += yp[h] * wsh[h * 128 + o];
      s1sh[idx] = acc;
    }
    __syncthreads();   // y0 free, W1 readers done

    // ---- step 4: stage Wa1 -> wsh, op_embs (84 f4) -> y0; raw a1 -> at1sh ---
    for (int i = t; i < 1536; i += 256) ((float4*)wsh)[i] = ((const float4*)Wa1)[i];
    if (t < 84) ((float4*)y0)[t] = ((const float4*)op_embs)[t];
    __syncthreads();
    for (int idx = t; idx < 896; idx += 256) {
      int op = idx >> 7, o = idx & 127;
      float a = ba1[o];
      for (int d = 0; d < 48; ++d) a += y0[op * 48 + d] * wsh[d * 128 + o];
      at1sh[idx] = a;                    // raw; sigmoid in step 5
    }
    __syncthreads();

    // ---- step 5: stage Wa2 -> wsh; a2, sigmoid both, finalize tables ----
    for (int i = t; i < 1536; i += 256) ((float4*)wsh)[i] = ((const float4*)Wa2)[i];
    __syncthreads();
    for (int idx = t; idx < 896; idx += 256) {
      int op = idx >> 7, o = idx & 127;
      float a2 = ba2[o];
      for (int d = 0; d < 48; ++d) a2 += y0[op * 48 + d] * wsh[d * 128 + o];
      float v1 = (op == 0) ? 0.f : sigmoidf_(at1sh[idx]);   // NONE mask baked in
      float v2 = (op == 0) ? 0.f : sigmoidf_(a2);
      at1sh[idx] = v1;
      at2sh[idx] = v2;                   // overwrites embedding scratch (dead)
      ws[WS_AT2F + idx] = v2;            // identical from all blocks: benign
    }
    __syncthreads();                     // wsh (Wa2) readers done -> y1 overlay ok

    // ---- step 6: wave w -> 4 configs, y1 rows into wsh[w*512 ..] ----
    const int w  = t >> 6, o2 = t & 63;
    const int cfg0 = blockIdx.x * 16 + w * 4;   // 331*16 = 5296: no overflow
    const float2* s1f = (const float2*)s1sh;    // [12][64]
    const float2* a1f = (const float2*)at1sh;   // [7][64]
    float* y1p = wsh + w * 512;                 // [4 configs][128]

    #pragma unroll
    for (int r = 0; r < 4; ++r) {
      int cfg = cfg0 + r;
      float2 v;
      if (cfg < NCFG_REAL) {
        int c = cfg / CPER, q = cfg % CPER;
        int i, b;
        if (q < 196)       { i = 2; b = 0; }
        else if (q < 637)  { i = 3; b = 196; }
        else if (q < 1421) { i = 4; b = 637; }
        else               { i = 5; b = 1421; }
        q -= b;
        int op2_ = q % 7; q /= 7;
        int f2_  = q % i; q /= i;
        int op1_ = q % 7;
        int f1_  = q / 7;
        int cb = c * 384;
        v = s1f[cb + i * 64 + o2];
        float2 A0 = a1f[op1_ * 64 + o2], B0 = s1f[cb + f1_ * 64 + o2];
        float2 A1 = a1f[op2_ * 64 + o2], B1 = s1f[cb + f2_ * 64 + o2];
        v.x += A0.x * B0.x + A1.x * B1.x;
        v.y += A0.y * B0.y + A1.y * B1.y;
      } else {                           // init node pseudo-config (no in-edges)
        int j = cfg - NCFG_REAL, c = j >> 1, i = j & 1;
        v = s1f[c * 384 + i * 64 + o2];
      }
      ((float2*)(y1p + r * 128))[o2] =
          make_float2(fmaxf(v.x, 0.f), fmaxf(v.y, 0.f));
    }
    __syncthreads();

    // ---- step 7: tab rows = y1 @ W2 -- R5/R9-proven scalar-accumulator gemm --
    const float2* W2f = (const float2*)W2;
    float ax0 = 0, ax1 = 0, ax2 = 0, ax3 = 0;
    float ay0 = 0, ay1 = 0, ay2 = 0, ay3 = 0;

    for (int h = 0; h < 128; h += 4) {
      float4 q0 = *(const float4*)(y1p + 0 * 128 + h);  // wave-broadcast LDS
      float4 q1 = *(const float4*)(y1p + 1 * 128 + h);
      float4 q2 = *(const float4*)(y1p + 2 * 128 + h);
      float4 q3 = *(const float4*)(y1p + 3 * 128 + h);
      #pragma unroll
      for (int j = 0; j < 4; ++j) {
        float2 wf = W2f[(h + j) * 64 + o2];
        float w0 = wf.x, w1 = wf.y, y;
        y = COMP4(q0, j); ax0 += y * w0; ay0 += y * w1;
        y = COMP4(q1, j); ax1 += y * w0; ay1 += y * w1;
        y = COMP4(q2, j); ax2 += y * w0; ay2 += y * w1;
        y = COMP4(q3, j); ax3 += y * w0; ay3 += y * w1;
      }
    }

    float2* tab = (float2*)(ws + WS_TAB);
    tab[(cfg0 + 0) * 64 + o2] = make_float2(ax0, ay0);
    tab[(cfg0 + 1) * 64 + o2] = make_float2(ax1, ay1);
    tab[(cfg0 + 2) * 64 + o2] = make_float2(ax2, ay2);
    tab[(cfg0 + 3) * 64 + o2] = make_float2(ax3, ay3);
  }

  // ---- device-scope visibility (per-XCD L2s not coherent), then grid sync --
  __threadfence();
  cg::this_grid().sync();
  __syncthreads();          // belt-and-braces before LDS overlay reuse

  // ================= phase 2: gather, 16 pairs per block ====================
  {
    int* archsh = (int*)wsh;              // overlay (phase-1 LDS dead)
    archsh[t] = archs[blockIdx.x * 256 + t];   // 512*256 = 8192*16 exact
    __syncthreads();

    const int pp = t >> 6;
    const int o2 = t & 63;
    // P = blockIdx.x*16 + g4*4 + pp; 16 and 4 are even -> c = P&1 = pp&1,
    // constant over g4: hoist S0/S1 (init pseudo-rows) out of the loop.
    const int c = pp & 1;

    const float2* tab = (const float2*)(ws + WS_TAB);
    const float2* a2f = (const float2*)(ws + WS_AT2F);

    const float2 S0 = tab[(NCFG_REAL + c * 2 + 0) * 64 + o2];
    const float2 S1 = tab[(NCFG_REAL + c * 2 + 1) * 64 + o2];

    #pragma unroll
    for (int g4 = 0; g4 < 4; ++g4) {
      const int P    = blockIdx.x * 16 + g4 * 4 + pp;
      const int base = g4 * 64 + pp * 16;

      int f[8], op[8];
      #pragma unroll
      for (int e = 0; e < 8; ++e) { f[e] = archsh[base + e]; op[e] = archsh[base + 8 + e]; }

      float2 S2, S3, S4, S5;
      {
        const int ib[4] = {0, 196, 637, 1421};
        #pragma unroll
        for (int i = 2; i < 6; ++i) {
          int e0 = 2 * (i - 2), e1 = e0 + 1;
          int cid = c * CPER + ib[i - 2] +
                    ((f[e0] * 7 + op[e0]) * i + f[e1]) * 7 + op[e1];
          float2 v = tab[cid * 64 + o2];
          if (i == 2) S2 = v; else if (i == 3) S3 = v;
          else if (i == 4) S4 = v; else S5 = v;
        }
      }
      float2 A2[8];
      #pragma unroll
      for (int e = 0; e < 8; ++e) A2[e] = a2f[op[e] * 64 + o2];

      float r0 = S2.x + S3.x + S4.x + S5.x;
      float r1 = S2.y + S3.y + S4.y + S5.y;
      #pragma unroll
      for (int e = 0; e < 8; ++e) {
        int fe = f[e];
        float sx, sy;
        if (fe == 0)      { sx = S0.x; sy = S0.y; }
        else if (fe == 1) { sx = S1.x; sy = S1.y; }
        else if (fe == 2) { sx = S2.x; sy = S2.y; }
        else if (fe == 3) { sx = S3.x; sy = S3.y; }
        else              { sx = S4.x; sy = S4.y; }
        r0 += A2[e].x * sx;
        r1 += A2[e].y * sy;
      }
      ((float2*)out)[P * 64 + o2] = make_float2(r0 * 0.25f, r1 * 0.25f);
    }
  }
}

// ===================== fallback A: proven two-kernel dedup path ============
__global__ __launch_bounds__(256) void config_kernel(
    const float* __restrict__ init_emb, const float* __restrict__ other_emb,
    const float* __restrict__ op_embs,  const float* __restrict__ Wx,
    const float* __restrict__ bx,       const float* __restrict__ W1,
    const float* __restrict__ Wa1,      const float* __restrict__ ba1,
    const float* __restrict__ W2,       const float* __restrict__ Wa2,
    const float* __restrict__ ba2,      float* __restrict__ ws)
{
  __shared__ __align__(16) float wsh[6144];
  __shared__ __align__(16) float s1sh[1536];
  __shared__ __align__(16) float at1sh[896];
  __shared__ __align__(16) float at2sh[896];
  __shared__ __align__(16) float y0[576];
  const int t = threadIdx.x;

  for (int i = t; i < 576; i += 256) ((float4*)wsh)[i] = ((const float4*)Wx)[i];
  if (t < 48)       ((float4*)at2sh)[t] = ((const float4*)init_emb)[t];
  else if (t < 72)  ((float4*)at2sh)[t] = ((const float4*)other_emb)[t - 48];
  else if (t < 84)  ((float4*)at2sh)[t] = ((const float4*)bx)[t - 72];
  __syncthreads();

  for (int idx = t; idx < 576; idx += 256) {
    int c = idx / 288, i = (idx / 48) % 6, h = idx % 48;
    const float* nptr = (i < 2) ? (at2sh + (c * 2 + i) * 48)
                                : (at2sh + 192 + c * 48);
    float acc = at2sh[288 + h];
    for (int d = 0; d < 48; ++d) acc += nptr[d] * wsh[d * 48 + h];
    y0[idx] = acc;
  }
  __syncthreads();

  for (int i = t; i < 1536; i += 256) ((float4*)wsh)[i] = ((const float4*)W1)[i];
  __syncthreads();
  for (int idx = t; idx < 1536; idx += 256) {
    int ci = idx >> 7, o = idx & 127;
    const float* yp = y0 + ci * 48;
    float acc = 0.f;
    for (int h = 0; h < 48; ++h) acc += yp[h] * wsh[h * 128 + o];
    s1sh[idx] = acc;
  }
  __syncthreads();

  for (int i = t; i < 1536; i += 256) ((float4*)wsh)[i] = ((const float4*)Wa1)[i];
  if (t < 84) ((float4*)y0)[t] = ((const float4*)op_embs)[t];
  __syncthreads();
  for (int idx = t; idx < 896; idx += 256) {
    int op = idx >> 7, o = idx & 127;
    float a = ba1[o];
    for (int d = 0; d < 48; ++d) a += y0[op * 48 + d] * wsh[d * 128 + o];
    at1sh[idx] = a;
  }
  __syncthreads();

  for (int i = t; i < 1536; i += 256) ((float4*)wsh)[i] = ((const float4*)Wa2)[i];
  __syncthreads();
  for (int idx = t; idx < 896; idx += 256) {
    int op = idx >> 7, o = idx & 127;
    float a2 = ba2[o];
    for (int d = 0; d < 48; ++d) a2 += y0[op * 48 + d] * wsh[d * 128 + o];
    float v1 = (op == 0) ? 0.f : sigmoidf_(at1sh[idx]);
    float v2 = (op == 0) ? 0.f : sigmoidf_(a2);
    at1sh[idx] = v1;
    at2sh[idx] = v2;
    ws[WS_AT2F + idx] = v2;
  }
  __syncthreads();

  const int w  = t >> 6, o2 = t & 63;
  const int cfg0 = blockIdx.x * 16 + w * 4;
  const float2* s1f = (const float2*)s1sh;
  const float2* a1f = (const float2*)at1sh;
  float* y1p = wsh + w * 512;

  #pragma unroll
  for (int r = 0; r < 4; ++r) {
    int cfg = cfg0 + r;
    float2 v;
    if (cfg < NCFG_REAL) {
      int c = cfg / CPER, q = cfg % CPER;
      int i, b;
      if (q < 196)       { i = 2; b = 0; }
      else if (q < 637)  { i = 3; b = 196; }
      else if (q < 1421) { i = 4; b = 637; }
      else               { i = 5; b = 1421; }
      q -= b;
      int op2_ = q % 7; q /= 7;
      int f2_  = q % i; q /= i;
      int op1_ = q % 7;
      int f1_  = q / 7;
      int cb = c * 384;
      v = s1f[cb + i * 64 + o2];
      float2 A0 = a1f[op1_ * 64 + o2], B0 = s1f[cb + f1_ * 64 + o2];
      float2 A1 = a1f[op2_ * 64 + o2], B1 = s1f[cb + f2_ * 64 + o2];
      v.x += A0.x * B0.x + A1.x * B1.x;
      v.y += A0.y * B0.y + A1.y * B1.y;
    } else {
      int j = cfg - NCFG_REAL, c = j >> 1, i = j & 1;
      v = s1f[c * 384 + i * 64 + o2];
    }
    ((float2*)(y1p + r * 128))[o2] =
        make_float2(fmaxf(v.x, 0.f), fmaxf(v.y, 0.f));
  }
  __syncthreads();

  const float2* W2f = (const float2*)W2;
  float ax0 = 0, ax1 = 0, ax2 = 0, ax3 = 0;
  float ay0 = 0, ay1 = 0, ay2 = 0, ay3 = 0;

  for (int h = 0; h < 128; h += 4) {
    float4 q0 = *(const float4*)(y1p + 0 * 128 + h);
    float4 q1 = *(const float4*)(y1p + 1 * 128 + h);
    float4 q2 = *(const float4*)(y1p + 2 * 128 + h);
    float4 q3 = *(const float4*)(y1p + 3 * 128 + h);
    #pragma unroll
    for (int j = 0; j < 4; ++j) {
      float2 wf = W2f[(h + j) * 64 + o2];
      float w0 = wf.x, w1 = wf.y, y;
      y = COMP4(q0, j); ax0 += y * w0; ay0 += y * w1;
      y = COMP4(q1, j); ax1 += y * w0; ay1 += y * w1;
      y = COMP4(q2, j); ax2 += y * w0; ay2 += y * w1;
      y = COMP4(q3, j); ax3 += y * w0; ay3 += y * w1;
    }
  }

  float2* tab = (float2*)(ws + WS_TAB);
  tab[(cfg0 + 0) * 64 + o2] = make_float2(ax0, ay0);
  tab[(cfg0 + 1) * 64 + o2] = make_float2(ax1, ay1);
  tab[(cfg0 + 2) * 64 + o2] = make_float2(ax2, ay2);
  tab[(cfg0 + 3) * 64 + o2] = make_float2(ax3, ay3);
}

__global__ __launch_bounds__(256) void gather_kernel(
    const int* __restrict__ archs, const float* __restrict__ ws,
    float* __restrict__ out)
{
  const int t  = threadIdx.x;
  const int pp = t >> 6;
  const int o2 = t & 63;
  const int P  = blockIdx.x * 4 + pp;
  const int c  = P & 1;

  __shared__ int archsh[64];
  if (t < 64) archsh[t] = archs[blockIdx.x * 64 + t];
  __syncthreads();

  int f[8], op[8];
  #pragma unroll
  for (int e = 0; e < 8; ++e) { f[e] = archsh[pp * 16 + e]; op[e] = archsh[pp * 16 + 8 + e]; }

  const float2* tab = (const float2*)(ws + WS_TAB);
  const float2* a2f = (const float2*)(ws + WS_AT2F);

  float2 S0 = tab[(NCFG_REAL + c * 2 + 0) * 64 + o2];
  float2 S1 = tab[(NCFG_REAL + c * 2 + 1) * 64 + o2];
  float2 S2, S3, S4, S5;
  {
    const int ib[4] = {0, 196, 637, 1421};
    #pragma unroll
    for (int i = 2; i < 6; ++i) {
      int e0 = 2 * (i - 2), e1 = e0 + 1;
      int cid = c * CPER + ib[i - 2] +
                ((f[e0] * 7 + op[e0]) * i + f[e1]) * 7 + op[e1];
      float2 v = tab[cid * 64 + o2];
      if (i == 2) S2 = v; else if (i == 3) S3 = v;
      else if (i == 4) S4 = v; else S5 = v;
    }
  }
  float2 A2[8];
  #pragma unroll
  for (int e = 0; e < 8; ++e) A2[e] = a2f[op[e] * 64 + o2];

  float r0 = S2.x + S3.x + S4.x + S5.x;
  float r1 = S2.y + S3.y + S4.y + S5.y;
  #pragma unroll
  for (int e = 0; e < 8; ++e) {
    int fe = f[e];
    float sx, sy;
    if (fe == 0)      { sx = S0.x; sy = S0.y; }
    else if (fe == 1) { sx = S1.x; sy = S1.y; }
    else if (fe == 2) { sx = S2.x; sy = S2.y; }
    else if (fe == 3) { sx = S3.x; sy = S3.y; }
    else              { sx = S4.x; sy = S4.y; }
    r0 += A2[e].x * sx;
    r1 += A2[e].y * sy;
  }
  ((float2*)out)[P * 64 + o2] = make_float2(r0 * 0.25f, r1 * 0.25f);
}

// ===================== fallback B: R9 verbatim (if ws too small) ============
#define FB_S1   0
#define FB_AT1  1536
#define FB_AT2  2432
#define FB_S2I  3328

__global__ __launch_bounds__(512) void precompute_kernel(
    const float* __restrict__ init_emb, const float* __restrict__ other_emb,
    const float* __restrict__ op_embs,  const float* __restrict__ Wx,
    const float* __restrict__ bx,       const float* __restrict__ W1,
    const float* __restrict__ Wa1,      const float* __restrict__ ba1,
    const float* __restrict__ W2,       const float* __restrict__ Wa2,
    const float* __restrict__ ba2,      float* __restrict__ ws)
{
  const int t   = threadIdx.x;
  const int blk = blockIdx.x;
  __shared__ float y0[576];
  __shared__ float s1sh[1536];
  for (int idx = t; idx < 576; idx += 512) {
    int c = idx / 288, i = (idx / 48) % 6, h = idx % 48;
    const float* nptr = (i < 2) ? (init_emb + (c * 2 + i) * 48)
                                : (other_emb + c * 48);
    float acc = bx[h];
    for (int d = 0; d < 48; ++d) acc += nptr[d] * Wx[d * 48 + h];
    y0[idx] = acc;
  }
  __syncthreads();
  for (int idx = t; idx < 1536; idx += 512) {
    int ci = idx >> 7, o = idx & 127;
    const float* yp = y0 + ci * 48;
    float acc = 0.f;
    for (int h = 0; h < 48; ++h) acc += yp[h] * W1[h * 128 + o];
    s1sh[idx] = acc;
    ws[FB_S1 + idx] = acc;
  }
  for (int idx = blk * 112 + t; idx < (blk + 1) * 112; idx += 512) {
    int op = idx >> 7, o = idx & 127;
    float a1 = ba1[o], a2 = ba2[o];
    for (int d = 0; d < 48; ++d) {
      float e = op_embs[op * 48 + d];
      a1 += e * Wa1[d * 128 + o];
      a2 += e * Wa2[d * 128 + o];
    }
    ws[FB_AT1 + idx] = (op == 0) ? 0.f : sigmoidf_(a1);
    ws[FB_AT2 + idx] = (op == 0) ? 0.f : sigmoidf_(a2);
  }
  __syncthreads();
  for (int idx = blk * 64 + t; idx < (blk + 1) * 64; idx += 512) {
    int c = idx >> 8, i = (idx >> 7) & 1, o = idx & 127;
    const float* sp = s1sh + (c * 6 + i) * 128;
    float acc = 0.f;
    for (int h = 0; h < 128; ++h) acc += fmaxf(sp[h], 0.f) * W2[h * 128 + o];
    ws[FB_S2I + idx] = acc;
  }
}

__global__ __launch_bounds__(256) void main_kernel(
    const int* __restrict__ archs, const float* __restrict__ W2,
    const float* __restrict__ ws, float* __restrict__ out)
{
  const int t  = threadIdx.x;
  const int pp = t >> 6;
  const int o2 = t & 63;
  const int P  = blockIdx.x * 4 + pp;
  const int c  = P & 1;
  __shared__ float y1sh[4][512];
  __shared__ int   archsh[64];
  if (t < 64) archsh[t] = archs[blockIdx.x * 64 + t];
  __syncthreads();
  int f[8], op[8];
  #pragma unroll
  for (int e = 0; e < 8; ++e) { f[e] = archsh[pp * 16 + e]; op[e] = archsh[pp * 16 + 8 + e]; }
  const float2* s1p = (const float2*)ws + c * 384;
  const float2* at1 = (const float2*)(ws + FB_AT1);
  const float2* at2 = (const float2*)(ws + FB_AT2);
  const float2* s2i = (const float2*)(ws + FB_S2I) + c * 128;
  float2 A2[8];
  #pragma unroll
  for (int e = 0; e < 8; ++e) A2[e] = at2[op[e] * 64 + o2];
  float2 S0 = s2i[o2], S1 = s2i[64 + o2];
  #pragma unroll
  for (int i = 0; i < 4; ++i) {
    float2 v = s1p[(2 + i) * 64 + o2];
    int e0 = 2 * i, e1 = 2 * i + 1;
    float2 A0 = at1[op[e0] * 64 + o2];
    float2 B0 = s1p[f[e0] * 64 + o2];
    float2 A1 = at1[op[e1] * 64 + o2];
    float2 B1 = s1p[f[e1] * 64 + o2];
    v.x += A0.x * B0.x + A1.x * B1.x;
    v.y += A0.y * B0.y + A1.y * B1.y;
    ((float2*)(y1sh[pp] + i * 128))[o2] =
        make_float2(fmaxf(v.x, 0.f), fmaxf(v.y, 0.f));
  }
  __syncthreads();
  const float* y1p = y1sh[pp];
  const float2* W2f = (const float2*)W2;
  float ax0 = 0, ax1 = 0, ax2 = 0, ax3 = 0;
  float ay0 = 0, ay1 = 0, ay2 = 0, ay3 = 0;
  for (int h = 0; h < 128; h += 4) {
    float4 q0 = *(const float4*)(y1p + 0 * 128 + h);
    float4 q1 = *(const float4*)(y1p + 1 * 128 + h);
    float4 q2 = *(const float4*)(y1p + 2 * 128 + h);
    float4 q3 = *(const float4*)(y1p + 3 * 128 + h);
    #pragma unroll
    for (int j = 0; j < 4; ++j) {
      float2 wf = W2f[(h + j) * 64 + o2];
      float w0 = wf.x, w1 = wf.y, y;
      y = COMP4(q0, j); ax0 += y * w0; ay0 += y * w1;
      y = COMP4(q1, j); ax1 += y * w0; ay1 += y * w1;
      y = COMP4(q2, j); ax2 += y * w0; ay2 += y * w1;
      y = COMP4(q3, j); ax3 += y * w0; ay3 += y * w1;
    }
  }
  float r0 = ax0 + ax1 + ax2 + ax3;
  float r1 = ay0 + ay1 + ay2 + ay3;
  #pragma unroll
  for (int e = 0; e < 8; ++e) {
    int fe = f[e];
    float sx, sy;
    if (fe == 0)      { sx = S0.x; sy = S0.y; }
    else if (fe == 1) { sx = S1.x; sy = S1.y; }
    else if (fe == 2) { sx = ax0; sy = ay0; }
    else if (fe == 3) { sx = ax1; sy = ay1; }
    else if (fe == 4) { sx = ax2; sy = ay2; }
    else              { sx = ax3; sy = ay3; }
    r0 += A2[e].x * sx;
    r1 += A2[e].y * sy;
  }
  ((float2*)out)[P * 64 + o2] = make_float2(r0 * 0.25f, r1 * 0.25f);
}

extern "C" void kernel_launch(void* const* d_in, const int* in_sizes, int n_in,
                              void* d_out, int out_size, void* d_ws, size_t ws_size,
                              hipStream_t stream) {
  const int* archs = (const int*)d_in[0];
  float* ws = (float*)d_ws;
  if (ws_size >= WS_NEED) {
    const float* init_emb  = (const float*)d_in[1];
    const float* other_emb = (const float*)d_in[2];
    const float* op_embs   = (const float*)d_in[3];
    const float* Wx_  = (const float*)d_in[4];
    const float* bx_  = (const float*)d_in[5];
    const float* W1_  = (const float*)d_in[6];
    const float* Wa1_ = (const float*)d_in[7];
    const float* ba1_ = (const float*)d_in[8];
    const float* W2_  = (const float*)d_in[9];
    const float* Wa2_ = (const float*)d_in[10];
    const float* ba2_ = (const float*)d_in[11];
    float* out_ = (float*)d_out;

    void* args[] = {(void*)&init_emb, (void*)&other_emb, (void*)&op_embs,
                    (void*)&Wx_,  (void*)&bx_,  (void*)&W1_,  (void*)&Wa1_,
                    (void*)&ba1_, (void*)&W2_,  (void*)&Wa2_, (void*)&ba2_,
                    (void*)&archs, (void*)&ws,  (void*)&out_};
    hipError_t err = hipLaunchCooperativeKernel(
        (const void*)fused_kernel, dim3(512), dim3(256), args, 0, stream);
    if (err != hipSuccess) {
      (void)hipGetLastError();   // clear sticky error, fall back to 2-kernel path
      config_kernel<<<331, 256, 0, stream>>>(
          init_emb, other_emb, op_embs, Wx_, bx_, W1_, Wa1_, ba1_, W2_, Wa2_,
          ba2_, ws);
      gather_kernel<<<NPAIR / 4, 256, 0, stream>>>(archs, ws, (float*)d_out);
    }
  } else {
    precompute_kernel<<<8, 512, 0, stream>>>(
        (const float*)d_in[1], (const float*)d_in[2], (const float*)d_in[3],
        (const float*)d_in[4], (const float*)d_in[5], (const float*)d_in[6],
        (const float*)d_in[7], (const float*)d_in[8], (const float*)d_in[9],
        (const float*)d_in[10], (const float*)d_in[11], ws);
    main_kernel<<<NPAIR / 4, 256, 0, stream>>>(archs, (const float*)d_in[9], ws,
                                               (float*)d_out);
  }
}

// Round 2
// 127.020 us; speedup vs baseline: 1.8554x; 1.8554x over previous
//
#include <hip/hip_runtime.h>

#define NPAIR 8192   // B*NCG

// ===================== config-deduplicated path =====================
// Node layer-1 output depends only on (c, i, f_s0, op_s0, f_s1, op_s1):
// 5292 real configs + 4 init pseudo-rows = 5296. config_kernel builds
// tab[cfg] = relu(y1_cfg) @ W2; gather_kernel is a pure gather/aggregate.
// R14 forensics: 256 threads, 4 waves x 4 configs, matvec with SCALAR
// accumulators (VGPR 56-68, zero spill) is the proven shape.
// R15 forensics: cooperative fusion FAILED (235us): cg grid.sync cost
// ~100us (VALUBusy 4.4% over 135us kernel) and cooperative-in-graph added
// ~100us more launch overhead. NEVER use cooperative launch here.
// R16: shorten config's serial chain instead:
//   - Wa1/Wa2 have zero intra-block reuse -> read direct from global
//     (coalesced 256B/wave, L2-warm), killing 2 staging passes + 2 barriers.
//   - s1/at1/at2 are independent -> one fused barrier-free region
//     (3328 outputs = 13*256 exact; range boundaries are x64 -> wave-uniform).
//   - Wx+W1 staged into separate LDS buffers at t0 (latency hidden by step 2).
//   Barriers 7 -> 4; LDS 52KB -> 3 blocks/CU (was 2).
#define NCFG_REAL 5292
#define NCFG      5296
#define CPER      2646
#define WS_AT2F   0         // at2 table [7][128] (row 0 zeroed)
#define WS_TAB    1024      // tab [NCFG][128]
#define WS_NEED   ((size_t)(1024 + NCFG * 128) * 4)

#define COMP4(v, j) ((j) == 0 ? (v).x : (j) == 1 ? (v).y : (j) == 2 ? (v).z : (v).w)

__device__ __forceinline__ float sigmoidf_(float x) {
  return 1.0f / (1.0f + __expf(-x));
}

// 331 blocks x 256 threads; 16 configs per block (331*16 = 5296 exact).
__global__ __launch_bounds__(256) void config_kernel(
    const float* __restrict__ init_emb, const float* __restrict__ other_emb,
    const float* __restrict__ op_embs,  const float* __restrict__ Wx,
    const float* __restrict__ bx,       const float* __restrict__ W1,
    const float* __restrict__ Wa1,      const float* __restrict__ ba1,
    const float* __restrict__ W2,       const float* __restrict__ Wa2,
    const float* __restrict__ ba2,      float* __restrict__ ws)
{
  __shared__ __align__(16) float wx_sh[2304];  // Wx 48x48
  __shared__ __align__(16) float w1_sh[6144];  // W1 48x128; step6 y1 overlay
  __shared__ __align__(16) float s1sh[1536];   // support1 [2][6][128]
  __shared__ __align__(16) float at1sh[896];   // sigmoid(a1) [7][128] row0=0
  __shared__ __align__(16) float at2sh[896];   // sigmoid(a2) [7][128] row0=0
  __shared__ __align__(16) float y0sh[576];    // y0 [2][6][48]
  __shared__ __align__(16) float embsh[336];   // init(192) other(96) bx(48)
  __shared__ __align__(16) float opsh[336];    // op_embs [7][48]
  const int t = threadIdx.x;

  // ---- step 1: stage Wx + W1 + embeddings + op_embs (all loads at t0) ----
  for (int i = t; i < 576; i += 256)  ((float4*)wx_sh)[i] = ((const float4*)Wx)[i];
  for (int i = t; i < 1536; i += 256) ((float4*)w1_sh)[i] = ((const float4*)W1)[i];
  if (t < 48)        ((float4*)embsh)[t]      = ((const float4*)init_emb)[t];
  else if (t < 72)   ((float4*)embsh)[t]      = ((const float4*)other_emb)[t - 48];
  else if (t < 84)   ((float4*)embsh)[t]      = ((const float4*)bx)[t - 72];
  else if (t < 168)  ((float4*)opsh)[t - 84]  = ((const float4*)op_embs)[t - 84];
  __syncthreads();

  // ---- step 2: y0[c][i][h] = node @ Wx + bx (all LDS operands) ----
  for (int idx = t; idx < 576; idx += 256) {
    int c = idx / 288, i = (idx / 48) % 6, h = idx % 48;
    const float* nptr = (i < 2) ? (embsh + (c * 2 + i) * 48)
                                : (embsh + 192 + c * 48);
    float acc = embsh[288 + h];
    for (int d = 0; d < 48; ++d) acc += nptr[d] * wx_sh[d * 48 + h];
    y0sh[idx] = acc;
  }
  __syncthreads();

  // ---- step 3: fused region: s1 (LDS W1) | at1 | at2 (global Wa1/Wa2) ----
  // 1536 + 896 + 896 = 3328 = 13*256; boundaries 1536/2432 are x64 ->
  // branches are wave-uniform. Wa1/Wa2 reads are coalesced (o consecutive
  // within a wave) and have no intra-block reuse, so no LDS staging.
  for (int idx = t; idx < 3328; idx += 256) {
    if (idx < 1536) {
      int ci = idx >> 7, o = idx & 127;
      const float* yp = y0sh + ci * 48;
      float acc = 0.f;
      for (int h = 0; h < 48; ++h) acc += yp[h] * w1_sh[h * 128 + o];
      s1sh[idx] = acc;
    } else if (idx < 2432) {
      int j = idx - 1536;
      int op = j >> 7, o = j & 127;
      float a = ba1[o];
      for (int d = 0; d < 48; ++d) a += opsh[op * 48 + d] * Wa1[d * 128 + o];
      at1sh[j] = (op == 0) ? 0.f : sigmoidf_(a);   // NONE mask baked in
    } else {
      int j = idx - 2432;
      int op = j >> 7, o = j & 127;
      float a = ba2[o];
      for (int d = 0; d < 48; ++d) a += opsh[op * 48 + d] * Wa2[d * 128 + o];
      float v2 = (op == 0) ? 0.f : sigmoidf_(a);
      at2sh[j] = v2;
      ws[WS_AT2F + j] = v2;          // identical from all blocks: benign
    }
  }
  __syncthreads();                    // also: w1_sh readers done -> y1 overlay

  // ---- step 6: wave w -> 4 configs, y1 rows into w1_sh[w*512 ..] ----
  const int w  = t >> 6, o2 = t & 63;
  const int cfg0 = blockIdx.x * 16 + w * 4;   // 331*16 = 5296: no overflow
  const float2* s1f = (const float2*)s1sh;    // [12][64]
  const float2* a1f = (const float2*)at1sh;   // [7][64]
  float* y1p = w1_sh + w * 512;               // [4 configs][128]

  #pragma unroll
  for (int r = 0; r < 4; ++r) {
    int cfg = cfg0 + r;
    float2 v;
    if (cfg < NCFG_REAL) {
      int c = cfg / CPER, q = cfg % CPER;
      int i, b;
      if (q < 196)       { i = 2; b = 0; }
      else if (q < 637)  { i = 3; b = 196; }
      else if (q < 1421) { i = 4; b = 637; }
      else               { i = 5; b = 1421; }
      q -= b;
      int op2_ = q % 7; q /= 7;
      int f2_  = q % i; q /= i;
      int op1_ = q % 7;
      int f1_  = q / 7;
      int cb = c * 384;
      v = s1f[cb + i * 64 + o2];
      float2 A0 = a1f[op1_ * 64 + o2], B0 = s1f[cb + f1_ * 64 + o2];
      float2 A1 = a1f[op2_ * 64 + o2], B1 = s1f[cb + f2_ * 64 + o2];
      v.x += A0.x * B0.x + A1.x * B1.x;
      v.y += A0.y * B0.y + A1.y * B1.y;
    } else {                           // init node pseudo-config (no in-edges)
      int j = cfg - NCFG_REAL, c = j >> 1, i = j & 1;
      v = s1f[c * 384 + i * 64 + o2];
    }
    ((float2*)(y1p + r * 128))[o2] =
        make_float2(fmaxf(v.x, 0.f), fmaxf(v.y, 0.f));
  }
  __syncthreads();

  // ---- step 7: tab rows = y1 @ W2 -- R5/R9-proven scalar-accumulator gemm --
  const float2* W2f = (const float2*)W2;
  float ax0 = 0, ax1 = 0, ax2 = 0, ax3 = 0;
  float ay0 = 0, ay1 = 0, ay2 = 0, ay3 = 0;

  for (int h = 0; h < 128; h += 4) {
    float4 q0 = *(const float4*)(y1p + 0 * 128 + h);  // wave-broadcast LDS
    float4 q1 = *(const float4*)(y1p + 1 * 128 + h);
    float4 q2 = *(const float4*)(y1p + 2 * 128 + h);
    float4 q3 = *(const float4*)(y1p + 3 * 128 + h);
    #pragma unroll
    for (int j = 0; j < 4; ++j) {
      float2 wf = W2f[(h + j) * 64 + o2];
      float w0 = wf.x, w1 = wf.y, y;
      y = COMP4(q0, j); ax0 += y * w0; ay0 += y * w1;
      y = COMP4(q1, j); ax1 += y * w0; ay1 += y * w1;
      y = COMP4(q2, j); ax2 += y * w0; ay2 += y * w1;
      y = COMP4(q3, j); ax3 += y * w0; ay3 += y * w1;
    }
  }

  float2* tab = (float2*)(ws + WS_TAB);
  tab[(cfg0 + 0) * 64 + o2] = make_float2(ax0, ay0);
  tab[(cfg0 + 1) * 64 + o2] = make_float2(ax1, ay1);
  tab[(cfg0 + 2) * 64 + o2] = make_float2(ax2, ay2);
  tab[(cfg0 + 3) * 64 + o2] = make_float2(ax3, ay3);
}

__global__ __launch_bounds__(256) void gather_kernel(
    const int* __restrict__ archs, const float* __restrict__ ws,
    float* __restrict__ out)
{
  const int t  = threadIdx.x;
  const int pp = t >> 6;
  const int o2 = t & 63;
  const int P  = blockIdx.x * 4 + pp;
  const int c  = P & 1;

  __shared__ int archsh[64];
  if (t < 64) archsh[t] = archs[blockIdx.x * 64 + t];
  __syncthreads();

  int f[8], op[8];
  #pragma unroll
  for (int e = 0; e < 8; ++e) { f[e] = archsh[pp * 16 + e]; op[e] = archsh[pp * 16 + 8 + e]; }

  const float2* tab = (const float2*)(ws + WS_TAB);
  const float2* a2f = (const float2*)(ws + WS_AT2F);

  float2 S0 = tab[(NCFG_REAL + c * 2 + 0) * 64 + o2];
  float2 S1 = tab[(NCFG_REAL + c * 2 + 1) * 64 + o2];
  float2 S2, S3, S4, S5;
  {
    const int ib[4] = {0, 196, 637, 1421};
    #pragma unroll
    for (int i = 2; i < 6; ++i) {
      int e0 = 2 * (i - 2), e1 = e0 + 1;
      int cid = c * CPER + ib[i - 2] +
                ((f[e0] * 7 + op[e0]) * i + f[e1]) * 7 + op[e1];
      float2 v = tab[cid * 64 + o2];
      if (i == 2) S2 = v; else if (i == 3) S3 = v;
      else if (i == 4) S4 = v; else S5 = v;
    }
  }
  float2 A2[8];
  #pragma unroll
  for (int e = 0; e < 8; ++e) A2[e] = a2f[op[e] * 64 + o2];

  float r0 = S2.x + S3.x + S4.x + S5.x;
  float r1 = S2.y + S3.y + S4.y + S5.y;
  #pragma unroll
  for (int e = 0; e < 8; ++e) {
    int fe = f[e];
    float sx, sy;
    if (fe == 0)      { sx = S0.x; sy = S0.y; }
    else if (fe == 1) { sx = S1.x; sy = S1.y; }
    else if (fe == 2) { sx = S2.x; sy = S2.y; }
    else if (fe == 3) { sx = S3.x; sy = S3.y; }
    else              { sx = S4.x; sy = S4.y; }
    r0 += A2[e].x * sx;
    r1 += A2[e].y * sy;
  }
  ((float2*)out)[P * 64 + o2] = make_float2(r0 * 0.25f, r1 * 0.25f);
}

// ===================== FALLBACK: R9 verbatim (if ws too small) ============
#define FB_S1   0
#define FB_AT1  1536
#define FB_AT2  2432
#define FB_S2I  3328

__global__ __launch_bounds__(512) void precompute_kernel(
    const float* __restrict__ init_emb, const float* __restrict__ other_emb,
    const float* __restrict__ op_embs,  const float* __restrict__ Wx,
    const float* __restrict__ bx,       const float* __restrict__ W1,
    const float* __restrict__ Wa1,      const float* __restrict__ ba1,
    const float* __restrict__ W2,       const float* __restrict__ Wa2,
    const float* __restrict__ ba2,      float* __restrict__ ws)
{
  const int t   = threadIdx.x;
  const int blk = blockIdx.x;
  __shared__ float y0[576];
  __shared__ float s1sh[1536];
  for (int idx = t; idx < 576; idx += 512) {
    int c = idx / 288, i = (idx / 48) % 6, h = idx % 48;
    const float* nptr = (i < 2) ? (init_emb + (c * 2 + i) * 48)
                                : (other_emb + c * 48);
    float acc = bx[h];
    for (int d = 0; d < 48; ++d) acc += nptr[d] * Wx[d * 48 + h];
    y0[idx] = acc;
  }
  __syncthreads();
  for (int idx = t; idx < 1536; idx += 512) {
    int ci = idx >> 7, o = idx & 127;
    const float* yp = y0 + ci * 48;
    float acc = 0.f;
    for (int h = 0; h < 48; ++h) acc += yp[h] * W1[h * 128 + o];
    s1sh[idx] = acc;
    ws[FB_S1 + idx] = acc;
  }
  for (int idx = blk * 112 + t; idx < (blk + 1) * 112; idx += 512) {
    int op = idx >> 7, o = idx & 127;
    float a1 = ba1[o], a2 = ba2[o];
    for (int d = 0; d < 48; ++d) {
      float e = op_embs[op * 48 + d];
      a1 += e * Wa1[d * 128 + o];
      a2 += e * Wa2[d * 128 + o];
    }
    ws[FB_AT1 + idx] = (op == 0) ? 0.f : sigmoidf_(a1);
    ws[FB_AT2 + idx] = (op == 0) ? 0.f : sigmoidf_(a2);
  }
  __syncthreads();
  for (int idx = blk * 64 + t; idx < (blk + 1) * 64; idx += 512) {
    int c = idx >> 8, i = (idx >> 7) & 1, o = idx & 127;
    const float* sp = s1sh + (c * 6 + i) * 128;
    float acc = 0.f;
    for (int h = 0; h < 128; ++h) acc += fmaxf(sp[h], 0.f) * W2[h * 128 + o];
    ws[FB_S2I + idx] = acc;
  }
}

__global__ __launch_bounds__(256) void main_kernel(
    const int* __restrict__ archs, const float* __restrict__ W2,
    const float* __restrict__ ws, float* __restrict__ out)
{
  const int t  = threadIdx.x;
  const int pp = t >> 6;
  const int o2 = t & 63;
  const int P  = blockIdx.x * 4 + pp;
  const int c  = P & 1;
  __shared__ float y1sh[4][512];
  __shared__ int   archsh[64];
  if (t < 64) archsh[t] = archs[blockIdx.x * 64 + t];
  __syncthreads();
  int f[8], op[8];
  #pragma unroll
  for (int e = 0; e < 8; ++e) { f[e] = archsh[pp * 16 + e]; op[e] = archsh[pp * 16 + 8 + e]; }
  const float2* s1p = (const float2*)ws + c * 384;
  const float2* at1 = (const float2*)(ws + FB_AT1);
  const float2* at2 = (const float2*)(ws + FB_AT2);
  const float2* s2i = (const float2*)(ws + FB_S2I) + c * 128;
  float2 A2[8];
  #pragma unroll
  for (int e = 0; e < 8; ++e) A2[e] = at2[op[e] * 64 + o2];
  float2 S0 = s2i[o2], S1 = s2i[64 + o2];
  #pragma unroll
  for (int i = 0; i < 4; ++i) {
    float2 v = s1p[(2 + i) * 64 + o2];
    int e0 = 2 * i, e1 = 2 * i + 1;
    float2 A0 = at1[op[e0] * 64 + o2];
    float2 B0 = s1p[f[e0] * 64 + o2];
    float2 A1 = at1[op[e1] * 64 + o2];
    float2 B1 = s1p[f[e1] * 64 + o2];
    v.x += A0.x * B0.x + A1.x * B1.x;
    v.y += A0.y * B0.y + A1.y * B1.y;
    ((float2*)(y1sh[pp] + i * 128))[o2] =
        make_float2(fmaxf(v.x, 0.f), fmaxf(v.y, 0.f));
  }
  __syncthreads();
  const float* y1p = y1sh[pp];
  const float2* W2f = (const float2*)W2;
  float ax0 = 0, ax1 = 0, ax2 = 0, ax3 = 0;
  float ay0 = 0, ay1 = 0, ay2 = 0, ay3 = 0;
  for (int h = 0; h < 128; h += 4) {
    float4 q0 = *(const float4*)(y1p + 0 * 128 + h);
    float4 q1 = *(const float4*)(y1p + 1 * 128 + h);
    float4 q2 = *(const float4*)(y1p + 2 * 128 + h);
    float4 q3 = *(const float4*)(y1p + 3 * 128 + h);
    #pragma unroll
    for (int j = 0; j < 4; ++j) {
      float2 wf = W2f[(h + j) * 64 + o2];
      float w0 = wf.x, w1 = wf.y, y;
      y = COMP4(q0, j); ax0 += y * w0; ay0 += y * w1;
      y = COMP4(q1, j); ax1 += y * w0; ay1 += y * w1;
      y = COMP4(q2, j); ax2 += y * w0; ay2 += y * w1;
      y = COMP4(q3, j); ax3 += y * w0; ay3 += y * w1;
    }
  }
  float r0 = ax0 + ax1 + ax2 + ax3;
  float r1 = ay0 + ay1 + ay2 + ay3;
  #pragma unroll
  for (int e = 0; e < 8; ++e) {
    int fe = f[e];
    float sx, sy;
    if (fe == 0)      { sx = S0.x; sy = S0.y; }
    else if (fe == 1) { sx = S1.x; sy = S1.y; }
    else if (fe == 2) { sx = ax0; sy = ay0; }
    else if (fe == 3) { sx = ax1; sy = ay1; }
    else if (fe == 4) { sx = ax2; sy = ay2; }
    else              { sx = ax3; sy = ay3; }
    r0 += A2[e].x * sx;
    r1 += A2[e].y * sy;
  }
  ((float2*)out)[P * 64 + o2] = make_float2(r0 * 0.25f, r1 * 0.25f);
}

extern "C" void kernel_launch(void* const* d_in, const int* in_sizes, int n_in,
                              void* d_out, int out_size, void* d_ws, size_t ws_size,
                              hipStream_t stream) {
  const int* archs = (const int*)d_in[0];
  float* ws = (float*)d_ws;
  if (ws_size >= WS_NEED) {
    config_kernel<<<331, 256, 0, stream>>>(
        (const float*)d_in[1], (const float*)d_in[2], (const float*)d_in[3],
        (const float*)d_in[4], (const float*)d_in[5], (const float*)d_in[6],
        (const float*)d_in[7], (const float*)d_in[8], (const float*)d_in[9],
        (const float*)d_in[10], (const float*)d_in[11], ws);
    gather_kernel<<<NPAIR / 4, 256, 0, stream>>>(archs, ws, (float*)d_out);
  } else {
    precompute_kernel<<<8, 512, 0, stream>>>(
        (const float*)d_in[1], (const float*)d_in[2], (const float*)d_in[3],
        (const float*)d_in[4], (const float*)d_in[5], (const float*)d_in[6],
        (const float*)d_in[7], (const float*)d_in[8], (const float*)d_in[9],
        (const float*)d_in[10], (const float*)d_in[11], ws);
    main_kernel<<<NPAIR / 4, 256, 0, stream>>>(archs, (const float*)d_in[9], ws,
                                               (float*)d_out);
  }
}

// Round 3
// 104.099 us; speedup vs baseline: 2.2640x; 1.2202x over previous
//
#include <hip/hip_runtime.h>

#define NPAIR 8192   // B*NCG

// ===================== config-deduplicated path =====================
// Node layer-1 output depends only on (c, i, f_s0, op_s0, f_s1, op_s1):
// 5292 real configs + 4 init pseudo-rows = 5296. config_kernel builds
// tab[cfg] = relu(y1_cfg) @ W2; gather_kernel is a pure gather/aggregate.
// R14: 256 threads, 4 waves, scalar accumulators (no spill) is the shape.
// R15: cooperative fusion FAILED (235us): grid.sync ~100us + coop launch
//   overhead ~100us. NEVER use cooperative launch here.
// R16 FAILED (127us): direct-global Wa reads = narrow 4B strided loads,
//   latency-exposed at ~1 block/CU (VALUBusy 8%). Stage wide or not at all.
// R17: grid <= 256 -> exactly 1 block/CU -> LDS can grow to ~100KB with no
//   concurrency loss. Stage ALL weights at t0 (one ~86KB coalesced burst,
//   single vmcnt wait), fuse s1|at1|at2 into one all-LDS region.
//   4 barriers (was 7), 1 staging round trip (was 4).
//   Grid 221 x 24 configs (221*24=5304>=5296, tail guarded).
#define NCFG_REAL 5292
#define NCFG      5296
#define CPER      2646
#define NBLK      221       // <= 256: one block per CU
#define WS_AT2F   0         // at2 table [7][128] (row 0 zeroed)
#define WS_TAB    1024      // tab [NCFG][128]
#define WS_NEED   ((size_t)(1024 + NCFG * 128) * 4)

#define COMP4(v, j) ((j) == 0 ? (v).x : (j) == 1 ? (v).y : (j) == 2 ? (v).z : (v).w)

__device__ __forceinline__ float sigmoidf_(float x) {
  return 1.0f / (1.0f + __expf(-x));
}

// 221 blocks x 256 threads; 24 configs per block, 6 per wave.
__global__ __launch_bounds__(256) void config_kernel(
    const float* __restrict__ init_emb, const float* __restrict__ other_emb,
    const float* __restrict__ op_embs,  const float* __restrict__ Wx,
    const float* __restrict__ bx,       const float* __restrict__ W1,
    const float* __restrict__ Wa1,      const float* __restrict__ ba1,
    const float* __restrict__ W2,       const float* __restrict__ Wa2,
    const float* __restrict__ ba2,      float* __restrict__ ws)
{
  __shared__ __align__(16) float wx_sh[2304];   // Wx 48x48
  __shared__ __align__(16) float w1_sh[6144];   // W1 48x128
  __shared__ __align__(16) float wa1sh[6144];   // Wa1 48x128; later y1 overlay
  __shared__ __align__(16) float wa2sh[6144];   // Wa2 48x128
  __shared__ __align__(16) float s1sh[1536];    // support1 [2][6][128]
  __shared__ __align__(16) float at1sh[896];    // sigmoid(a1) [7][128] row0=0
  __shared__ __align__(16) float at2sh[896];    // sigmoid(a2) [7][128] row0=0
  __shared__ __align__(16) float y0sh[576];     // y0 [2][6][48]
  __shared__ __align__(16) float embsh[336];    // init(192) other(96) bx(48)
  __shared__ __align__(16) float opsh[336];     // op_embs [7][48]
  const int t = threadIdx.x;

  // ---- step 1: stage EVERYTHING (one wide burst, single wait) ----
  for (int i = t; i < 576; i += 256)  ((float4*)wx_sh)[i] = ((const float4*)Wx)[i];
  for (int i = t; i < 1536; i += 256) ((float4*)w1_sh)[i] = ((const float4*)W1)[i];
  for (int i = t; i < 1536; i += 256) ((float4*)wa1sh)[i] = ((const float4*)Wa1)[i];
  for (int i = t; i < 1536; i += 256) ((float4*)wa2sh)[i] = ((const float4*)Wa2)[i];
  if (t < 48)        ((float4*)embsh)[t]     = ((const float4*)init_emb)[t];
  else if (t < 72)   ((float4*)embsh)[t]     = ((const float4*)other_emb)[t - 48];
  else if (t < 84)   ((float4*)embsh)[t]     = ((const float4*)bx)[t - 72];
  else if (t < 168)  ((float4*)opsh)[t - 84] = ((const float4*)op_embs)[t - 84];
  __syncthreads();

  // ---- step 2: y0[c][i][h] = node @ Wx + bx (all LDS operands) ----
  for (int idx = t; idx < 576; idx += 256) {
    int c = idx / 288, i = (idx / 48) % 6, h = idx % 48;
    const float* nptr = (i < 2) ? (embsh + (c * 2 + i) * 48)
                                : (embsh + 192 + c * 48);
    float acc = embsh[288 + h];
    for (int d = 0; d < 48; ++d) acc += nptr[d] * wx_sh[d * 48 + h];
    y0sh[idx] = acc;
  }
  __syncthreads();

  // ---- step 3: fused all-LDS region: s1 | at1 final | at2 final ----
  // 1536 + 896 + 896 = 3328 = 13*256. Boundary 1536 is wave-exact; the
  // 2432 boundary splits an iteration at t=128 (wave-uniform: waves 0-1
  // do at1, waves 2-3 do at2). Every operand is in LDS.
  for (int idx = t; idx < 3328; idx += 256) {
    if (idx < 1536) {
      int ci = idx >> 7, o = idx & 127;
      const float* yp = y0sh + ci * 48;
      float acc = 0.f;
      for (int h = 0; h < 48; ++h) acc += yp[h] * w1_sh[h * 128 + o];
      s1sh[idx] = acc;
    } else if (idx < 2432) {
      int j = idx - 1536;
      int op = j >> 7, o = j & 127;
      float a = ba1[o];
      for (int d = 0; d < 48; ++d) a += opsh[op * 48 + d] * wa1sh[d * 128 + o];
      at1sh[j] = (op == 0) ? 0.f : sigmoidf_(a);   // NONE mask baked in
    } else {
      int j = idx - 2432;
      int op = j >> 7, o = j & 127;
      float a2 = ba2[o];
      for (int d = 0; d < 48; ++d) a2 += opsh[op * 48 + d] * wa2sh[d * 128 + o];
      float v2 = (op == 0) ? 0.f : sigmoidf_(a2);
      at2sh[j] = v2;
      if (blockIdx.x == 0) ws[WS_AT2F + j] = v2;   // write once, not 221x
    }
  }
  __syncthreads();                    // wa1sh readers done -> y1 overlay ok

  // ---- step 6: wave w -> 6 configs, y1 rows into wa1sh[w*768 ..] ----
  const int w  = t >> 6, o2 = t & 63;
  const int cfg0 = blockIdx.x * 24 + w * 6;   // up to 5303; tail guarded
  const float2* s1f = (const float2*)s1sh;    // [12][64]
  const float2* a1f = (const float2*)at1sh;   // [7][64]
  float* y1p = wa1sh + w * 768;               // [6 configs][128]

  #pragma unroll
  for (int r = 0; r < 6; ++r) {
    int cfg = cfg0 + r;
    float2 v;
    if (cfg < NCFG_REAL) {
      int c = cfg / CPER, q = cfg % CPER;
      int i, b;
      if (q < 196)       { i = 2; b = 0; }
      else if (q < 637)  { i = 3; b = 196; }
      else if (q < 1421) { i = 4; b = 637; }
      else               { i = 5; b = 1421; }
      q -= b;
      int op2_ = q % 7; q /= 7;
      int f2_  = q % i; q /= i;
      int op1_ = q % 7;
      int f1_  = q / 7;
      int cb = c * 384;
      v = s1f[cb + i * 64 + o2];
      float2 A0 = a1f[op1_ * 64 + o2], B0 = s1f[cb + f1_ * 64 + o2];
      float2 A1 = a1f[op2_ * 64 + o2], B1 = s1f[cb + f2_ * 64 + o2];
      v.x += A0.x * B0.x + A1.x * B1.x;
      v.y += A0.y * B0.y + A1.y * B1.y;
    } else if (cfg < NCFG) {           // init node pseudo-config (no in-edges)
      int j = cfg - NCFG_REAL, c = j >> 1, i = j & 1;
      v = s1f[c * 384 + i * 64 + o2];
    } else {                           // tail slot (block 220 only)
      v = make_float2(0.f, 0.f);
    }
    ((float2*)(y1p + r * 128))[o2] =
        make_float2(fmaxf(v.x, 0.f), fmaxf(v.y, 0.f));
  }
  __syncthreads();

  // ---- step 7: tab rows = y1 @ W2 -- scalar-accumulator gemm, 6 configs ----
  const float2* W2f = (const float2*)W2;
  float ax0 = 0, ax1 = 0, ax2 = 0, ax3 = 0, ax4 = 0, ax5 = 0;
  float ay0 = 0, ay1 = 0, ay2 = 0, ay3 = 0, ay4 = 0, ay5 = 0;

  for (int h = 0; h < 128; h += 4) {
    float4 q0 = *(const float4*)(y1p + 0 * 128 + h);  // wave-broadcast LDS
    float4 q1 = *(const float4*)(y1p + 1 * 128 + h);
    float4 q2 = *(const float4*)(y1p + 2 * 128 + h);
    float4 q3 = *(const float4*)(y1p + 3 * 128 + h);
    float4 q4 = *(const float4*)(y1p + 4 * 128 + h);
    float4 q5 = *(const float4*)(y1p + 5 * 128 + h);
    #pragma unroll
    for (int j = 0; j < 4; ++j) {
      float2 wf = W2f[(h + j) * 64 + o2];
      float w0 = wf.x, w1 = wf.y, y;
      y = COMP4(q0, j); ax0 += y * w0; ay0 += y * w1;
      y = COMP4(q1, j); ax1 += y * w0; ay1 += y * w1;
      y = COMP4(q2, j); ax2 += y * w0; ay2 += y * w1;
      y = COMP4(q3, j); ax3 += y * w0; ay3 += y * w1;
      y = COMP4(q4, j); ax4 += y * w0; ay4 += y * w1;
      y = COMP4(q5, j); ax5 += y * w0; ay5 += y * w1;
    }
  }

  float2* tab = (float2*)(ws + WS_TAB);
  if (cfg0 + 0 < NCFG) tab[(cfg0 + 0) * 64 + o2] = make_float2(ax0, ay0);
  if (cfg0 + 1 < NCFG) tab[(cfg0 + 1) * 64 + o2] = make_float2(ax1, ay1);
  if (cfg0 + 2 < NCFG) tab[(cfg0 + 2) * 64 + o2] = make_float2(ax2, ay2);
  if (cfg0 + 3 < NCFG) tab[(cfg0 + 3) * 64 + o2] = make_float2(ax3, ay3);
  if (cfg0 + 4 < NCFG) tab[(cfg0 + 4) * 64 + o2] = make_float2(ax4, ay4);
  if (cfg0 + 5 < NCFG) tab[(cfg0 + 5) * 64 + o2] = make_float2(ax5, ay5);
}

__global__ __launch_bounds__(256) void gather_kernel(
    const int* __restrict__ archs, const float* __restrict__ ws,
    float* __restrict__ out)
{
  const int t  = threadIdx.x;
  const int pp = t >> 6;
  const int o2 = t & 63;
  const int P  = blockIdx.x * 4 + pp;
  const int c  = P & 1;

  __shared__ int archsh[64];
  if (t < 64) archsh[t] = archs[blockIdx.x * 64 + t];
  __syncthreads();

  int f[8], op[8];
  #pragma unroll
  for (int e = 0; e < 8; ++e) { f[e] = archsh[pp * 16 + e]; op[e] = archsh[pp * 16 + 8 + e]; }

  const float2* tab = (const float2*)(ws + WS_TAB);
  const float2* a2f = (const float2*)(ws + WS_AT2F);

  float2 S0 = tab[(NCFG_REAL + c * 2 + 0) * 64 + o2];
  float2 S1 = tab[(NCFG_REAL + c * 2 + 1) * 64 + o2];
  float2 S2, S3, S4, S5;
  {
    const int ib[4] = {0, 196, 637, 1421};
    #pragma unroll
    for (int i = 2; i < 6; ++i) {
      int e0 = 2 * (i - 2), e1 = e0 + 1;
      int cid = c * CPER + ib[i - 2] +
                ((f[e0] * 7 + op[e0]) * i + f[e1]) * 7 + op[e1];
      float2 v = tab[cid * 64 + o2];
      if (i == 2) S2 = v; else if (i == 3) S3 = v;
      else if (i == 4) S4 = v; else S5 = v;
    }
  }
  float2 A2[8];
  #pragma unroll
  for (int e = 0; e < 8; ++e) A2[e] = a2f[op[e] * 64 + o2];

  float r0 = S2.x + S3.x + S4.x + S5.x;
  float r1 = S2.y + S3.y + S4.y + S5.y;
  #pragma unroll
  for (int e = 0; e < 8; ++e) {
    int fe = f[e];
    float sx, sy;
    if (fe == 0)      { sx = S0.x; sy = S0.y; }
    else if (fe == 1) { sx = S1.x; sy = S1.y; }
    else if (fe == 2) { sx = S2.x; sy = S2.y; }
    else if (fe == 3) { sx = S3.x; sy = S3.y; }
    else              { sx = S4.x; sy = S4.y; }
    r0 += A2[e].x * sx;
    r1 += A2[e].y * sy;
  }
  ((float2*)out)[P * 64 + o2] = make_float2(r0 * 0.25f, r1 * 0.25f);
}

// ===================== FALLBACK: R9 verbatim (if ws too small) ============
#define FB_S1   0
#define FB_AT1  1536
#define FB_AT2  2432
#define FB_S2I  3328

__global__ __launch_bounds__(512) void precompute_kernel(
    const float* __restrict__ init_emb, const float* __restrict__ other_emb,
    const float* __restrict__ op_embs,  const float* __restrict__ Wx,
    const float* __restrict__ bx,       const float* __restrict__ W1,
    const float* __restrict__ Wa1,      const float* __restrict__ ba1,
    const float* __restrict__ W2,       const float* __restrict__ Wa2,
    const float* __restrict__ ba2,      float* __restrict__ ws)
{
  const int t   = threadIdx.x;
  const int blk = blockIdx.x;
  __shared__ float y0[576];
  __shared__ float s1sh[1536];
  for (int idx = t; idx < 576; idx += 512) {
    int c = idx / 288, i = (idx / 48) % 6, h = idx % 48;
    const float* nptr = (i < 2) ? (init_emb + (c * 2 + i) * 48)
                                : (other_emb + c * 48);
    float acc = bx[h];
    for (int d = 0; d < 48; ++d) acc += nptr[d] * Wx[d * 48 + h];
    y0[idx] = acc;
  }
  __syncthreads();
  for (int idx = t; idx < 1536; idx += 512) {
    int ci = idx >> 7, o = idx & 127;
    const float* yp = y0 + ci * 48;
    float acc = 0.f;
    for (int h = 0; h < 48; ++h) acc += yp[h] * W1[h * 128 + o];
    s1sh[idx] = acc;
    ws[FB_S1 + idx] = acc;
  }
  for (int idx = blk * 112 + t; idx < (blk + 1) * 112; idx += 512) {
    int op = idx >> 7, o = idx & 127;
    float a1 = ba1[o], a2 = ba2[o];
    for (int d = 0; d < 48; ++d) {
      float e = op_embs[op * 48 + d];
      a1 += e * Wa1[d * 128 + o];
      a2 += e * Wa2[d * 128 + o];
    }
    ws[FB_AT1 + idx] = (op == 0) ? 0.f : sigmoidf_(a1);
    ws[FB_AT2 + idx] = (op == 0) ? 0.f : sigmoidf_(a2);
  }
  __syncthreads();
  for (int idx = blk * 64 + t; idx < (blk + 1) * 64; idx += 512) {
    int c = idx >> 8, i = (idx >> 7) & 1, o = idx & 127;
    const float* sp = s1sh + (c * 6 + i) * 128;
    float acc = 0.f;
    for (int h = 0; h < 128; ++h) acc += fmaxf(sp[h], 0.f) * W2[h * 128 + o];
    ws[FB_S2I + idx] = acc;
  }
}

__global__ __launch_bounds__(256) void main_kernel(
    const int* __restrict__ archs, const float* __restrict__ W2,
    const float* __restrict__ ws, float* __restrict__ out)
{
  const int t  = threadIdx.x;
  const int pp = t >> 6;
  const int o2 = t & 63;
  const int P  = blockIdx.x * 4 + pp;
  const int c  = P & 1;
  __shared__ float y1sh[4][512];
  __shared__ int   archsh[64];
  if (t < 64) archsh[t] = archs[blockIdx.x * 64 + t];
  __syncthreads();
  int f[8], op[8];
  #pragma unroll
  for (int e = 0; e < 8; ++e) { f[e] = archsh[pp * 16 + e]; op[e] = archsh[pp * 16 + 8 + e]; }
  const float2* s1p = (const float2*)ws + c * 384;
  const float2* at1 = (const float2*)(ws + FB_AT1);
  const float2* at2 = (const float2*)(ws + FB_AT2);
  const float2* s2i = (const float2*)(ws + FB_S2I) + c * 128;
  float2 A2[8];
  #pragma unroll
  for (int e = 0; e < 8; ++e) A2[e] = at2[op[e] * 64 + o2];
  float2 S0 = s2i[o2], S1 = s2i[64 + o2];
  #pragma unroll
  for (int i = 0; i < 4; ++i) {
    float2 v = s1p[(2 + i) * 64 + o2];
    int e0 = 2 * i, e1 = 2 * i + 1;
    float2 A0 = at1[op[e0] * 64 + o2];
    float2 B0 = s1p[f[e0] * 64 + o2];
    float2 A1 = at1[op[e1] * 64 + o2];
    float2 B1 = s1p[f[e1] * 64 + o2];
    v.x += A0.x * B0.x + A1.x * B1.x;
    v.y += A0.y * B0.y + A1.y * B1.y;
    ((float2*)(y1sh[pp] + i * 128))[o2] =
        make_float2(fmaxf(v.x, 0.f), fmaxf(v.y, 0.f));
  }
  __syncthreads();
  const float* y1p = y1sh[pp];
  const float2* W2f = (const float2*)W2;
  float ax0 = 0, ax1 = 0, ax2 = 0, ax3 = 0;
  float ay0 = 0, ay1 = 0, ay2 = 0, ay3 = 0;
  for (int h = 0; h < 128; h += 4) {
    float4 q0 = *(const float4*)(y1p + 0 * 128 + h);
    float4 q1 = *(const float4*)(y1p + 1 * 128 + h);
    float4 q2 = *(const float4*)(y1p + 2 * 128 + h);
    float4 q3 = *(const float4*)(y1p + 3 * 128 + h);
    #pragma unroll
    for (int j = 0; j < 4; ++j) {
      float2 wf = W2f[(h + j) * 64 + o2];
      float w0 = wf.x, w1 = wf.y, y;
      y = COMP4(q0, j); ax0 += y * w0; ay0 += y * w1;
      y = COMP4(q1, j); ax1 += y * w0; ay1 += y * w1;
      y = COMP4(q2, j); ax2 += y * w0; ay2 += y * w1;
      y = COMP4(q3, j); ax3 += y * w0; ay3 += y * w1;
    }
  }
  float r0 = ax0 + ax1 + ax2 + ax3;
  float r1 = ay0 + ay1 + ay2 + ay3;
  #pragma unroll
  for (int e = 0; e < 8; ++e) {
    int fe = f[e];
    float sx, sy;
    if (fe == 0)      { sx = S0.x; sy = S0.y; }
    else if (fe == 1) { sx = S1.x; sy = S1.y; }
    else if (fe == 2) { sx = ax0; sy = ay0; }
    else if (fe == 3) { sx = ax1; sy = ay1; }
    else if (fe == 4) { sx = ax2; sy = ay2; }
    else              { sx = ax3; sy = ay3; }
    r0 += A2[e].x * sx;
    r1 += A2[e].y * sy;
  }
  ((float2*)out)[P * 64 + o2] = make_float2(r0 * 0.25f, r1 * 0.25f);
}

extern "C" void kernel_launch(void* const* d_in, const int* in_sizes, int n_in,
                              void* d_out, int out_size, void* d_ws, size_t ws_size,
                              hipStream_t stream) {
  const int* archs = (const int*)d_in[0];
  float* ws = (float*)d_ws;
  if (ws_size >= WS_NEED) {
    config_kernel<<<NBLK, 256, 0, stream>>>(
        (const float*)d_in[1], (const float*)d_in[2], (const float*)d_in[3],
        (const float*)d_in[4], (const float*)d_in[5], (const float*)d_in[6],
        (const float*)d_in[7], (const float*)d_in[8], (const float*)d_in[9],
        (const float*)d_in[10], (const float*)d_in[11], ws);
    gather_kernel<<<NPAIR / 4, 256, 0, stream>>>(archs, ws, (float*)d_out);
  } else {
    precompute_kernel<<<8, 512, 0, stream>>>(
        (const float*)d_in[1], (const float*)d_in[2], (const float*)d_in[3],
        (const float*)d_in[4], (const float*)d_in[5], (const float*)d_in[6],
        (const float*)d_in[7], (const float*)d_in[8], (const float*)d_in[9],
        (const float*)d_in[10], (const float*)d_in[11], ws);
    main_kernel<<<NPAIR / 4, 256, 0, stream>>>(archs, (const float*)d_in[9], ws,
                                               (float*)d_out);
  }
}

// Round 4
// 100.811 us; speedup vs baseline: 2.3378x; 1.0326x over previous
//
#include <hip/hip_runtime.h>

#define NPAIR 8192   // B*NCG

// ===================== config-deduplicated path =====================
// Node layer-1 output depends only on (c, i, f_s0, op_s0, f_s1, op_s1):
// 5292 real configs + 4 init pseudo-rows = 5296. config_kernel builds
// tab[cfg] = relu(y1_cfg) @ W2; gather_kernel is a pure gather/aggregate.
// R14: scalar accumulators (no indexed register arrays!) -- indexed arrays
//   at 512 threads went to scratch. Scalars are safe at any block size.
// R15: cooperative fusion FAILED (235us): grid.sync ~100us + coop launch
//   overhead ~100us. NEVER use cooperative launch here.
// R16 FAILED (127us): narrow strided Wa loads latency-exposed at ~1 wave/SIMD.
// R17 (104us): stage ALL weights at t0 (one ~86KB burst), fuse s1|at1|at2,
//   4 barriers. config ~25us. Forensics: grid 221 blocks x 256 thr on 256
//   CUs = 1 wave/SIMD -> every LDS chain latency-exposed. Occupancy counter
//   was grid-limited, not resource-limited.
// R18: same structure, 512 threads/block (8 waves -> 2 waves/SIMD, 2x
//   latency hiding; per-wave work halves). 221 blocks x 24 cfg, 3 cfg/wave.
//   Budget model: 41us ws-poison fill (harness, fixed) + config + ~38us
//   gather+gaps. This round targets config 25 -> ~13.
#define NCFG_REAL 5292
#define NCFG      5296
#define CPER      2646
#define NBLK      221       // <= 256: single wave of blocks, no tail round
#define WS_AT2F   0         // at2 table [7][128] (row 0 zeroed)
#define WS_TAB    1024      // tab [NCFG][128]
#define WS_NEED   ((size_t)(1024 + NCFG * 128) * 4)

#define COMP4(v, j) ((j) == 0 ? (v).x : (j) == 1 ? (v).y : (j) == 2 ? (v).z : (v).w)

__device__ __forceinline__ float sigmoidf_(float x) {
  return 1.0f / (1.0f + __expf(-x));
}

// 221 blocks x 512 threads; 24 configs per block, 3 per wave.
__global__ __launch_bounds__(512) void config_kernel(
    const float* __restrict__ init_emb, const float* __restrict__ other_emb,
    const float* __restrict__ op_embs,  const float* __restrict__ Wx,
    const float* __restrict__ bx,       const float* __restrict__ W1,
    const float* __restrict__ Wa1,      const float* __restrict__ ba1,
    const float* __restrict__ W2,       const float* __restrict__ Wa2,
    const float* __restrict__ ba2,      float* __restrict__ ws)
{
  __shared__ __align__(16) float wx_sh[2304];   // Wx 48x48
  __shared__ __align__(16) float w1_sh[6144];   // W1 48x128
  __shared__ __align__(16) float wa1sh[6144];   // Wa1 48x128; later y1 overlay
  __shared__ __align__(16) float wa2sh[6144];   // Wa2 48x128
  __shared__ __align__(16) float s1sh[1536];    // support1 [2][6][128]
  __shared__ __align__(16) float at1sh[896];    // sigmoid(a1) [7][128] row0=0
  __shared__ __align__(16) float at2sh[896];    // sigmoid(a2) [7][128] row0=0
  __shared__ __align__(16) float y0sh[576];     // y0 [2][6][48]
  __shared__ __align__(16) float embsh[336];    // init(192) other(96) bx(48)
  __shared__ __align__(16) float opsh[336];     // op_embs [7][48]
  const int t = threadIdx.x;

  // ---- step 1: stage EVERYTHING (one wide burst, single wait) ----
  for (int i = t; i < 576; i += 512)  ((float4*)wx_sh)[i] = ((const float4*)Wx)[i];
  for (int i = t; i < 1536; i += 512) ((float4*)w1_sh)[i] = ((const float4*)W1)[i];
  for (int i = t; i < 1536; i += 512) ((float4*)wa1sh)[i] = ((const float4*)Wa1)[i];
  for (int i = t; i < 1536; i += 512) ((float4*)wa2sh)[i] = ((const float4*)Wa2)[i];
  if (t < 48)        ((float4*)embsh)[t]     = ((const float4*)init_emb)[t];
  else if (t < 72)   ((float4*)embsh)[t]     = ((const float4*)other_emb)[t - 48];
  else if (t < 84)   ((float4*)embsh)[t]     = ((const float4*)bx)[t - 72];
  else if (t < 168)  ((float4*)opsh)[t - 84] = ((const float4*)op_embs)[t - 84];
  __syncthreads();

  // ---- step 2: y0[c][i][h] = node @ Wx + bx (all LDS operands) ----
  for (int idx = t; idx < 576; idx += 512) {
    int c = idx / 288, i = (idx / 48) % 6, h = idx % 48;
    const float* nptr = (i < 2) ? (embsh + (c * 2 + i) * 48)
                                : (embsh + 192 + c * 48);
    float acc = embsh[288 + h];
    for (int d = 0; d < 48; ++d) acc += nptr[d] * wx_sh[d * 48 + h];
    y0sh[idx] = acc;
  }
  __syncthreads();

  // ---- step 3: fused all-LDS region: s1 | at1 final | at2 final ----
  // 1536 + 896 + 896 = 3328. With 512 threads: branch at 1536 = 3*512
  // (iteration-exact); branch at 2432 lands at t=384 within iteration 4
  // (384 = 6*64 -> wave-uniform). Every operand is in LDS.
  for (int idx = t; idx < 3328; idx += 512) {
    if (idx < 1536) {
      int ci = idx >> 7, o = idx & 127;
      const float* yp = y0sh + ci * 48;
      float acc = 0.f;
      for (int h = 0; h < 48; ++h) acc += yp[h] * w1_sh[h * 128 + o];
      s1sh[idx] = acc;
    } else if (idx < 2432) {
      int j = idx - 1536;
      int op = j >> 7, o = j & 127;
      float a = ba1[o];
      for (int d = 0; d < 48; ++d) a += opsh[op * 48 + d] * wa1sh[d * 128 + o];
      at1sh[j] = (op == 0) ? 0.f : sigmoidf_(a);   // NONE mask baked in
    } else {
      int j = idx - 2432;
      int op = j >> 7, o = j & 127;
      float a2 = ba2[o];
      for (int d = 0; d < 48; ++d) a2 += opsh[op * 48 + d] * wa2sh[d * 128 + o];
      float v2 = (op == 0) ? 0.f : sigmoidf_(a2);
      at2sh[j] = v2;
      if (blockIdx.x == 0) ws[WS_AT2F + j] = v2;   // write once, not 221x
    }
  }
  __syncthreads();                    // wa1sh readers done -> y1 overlay ok

  // ---- step 6: wave w -> 3 configs, y1 rows into wa1sh[w*384 ..] ----
  const int w  = t >> 6, o2 = t & 63;          // w in [0,8)
  const int cfg0 = blockIdx.x * 24 + w * 3;    // up to 5303; tail guarded
  const float2* s1f = (const float2*)s1sh;     // [12][64]
  const float2* a1f = (const float2*)at1sh;    // [7][64]
  float* y1p = wa1sh + w * 384;                // [3 configs][128]

  #pragma unroll
  for (int r = 0; r < 3; ++r) {
    int cfg = cfg0 + r;
    float2 v;
    if (cfg < NCFG_REAL) {
      int c = cfg / CPER, q = cfg % CPER;
      int i, b;
      if (q < 196)       { i = 2; b = 0; }
      else if (q < 637)  { i = 3; b = 196; }
      else if (q < 1421) { i = 4; b = 637; }
      else               { i = 5; b = 1421; }
      q -= b;
      int op2_ = q % 7; q /= 7;
      int f2_  = q % i; q /= i;
      int op1_ = q % 7;
      int f1_  = q / 7;
      int cb = c * 384;
      v = s1f[cb + i * 64 + o2];
      float2 A0 = a1f[op1_ * 64 + o2], B0 = s1f[cb + f1_ * 64 + o2];
      float2 A1 = a1f[op2_ * 64 + o2], B1 = s1f[cb + f2_ * 64 + o2];
      v.x += A0.x * B0.x + A1.x * B1.x;
      v.y += A0.y * B0.y + A1.y * B1.y;
    } else if (cfg < NCFG) {           // init node pseudo-config (no in-edges)
      int j = cfg - NCFG_REAL, c = j >> 1, i = j & 1;
      v = s1f[c * 384 + i * 64 + o2];
    } else {                           // tail slot (block 220 only)
      v = make_float2(0.f, 0.f);
    }
    ((float2*)(y1p + r * 128))[o2] =
        make_float2(fmaxf(v.x, 0.f), fmaxf(v.y, 0.f));
  }
  __syncthreads();

  // ---- step 7: tab rows = y1 @ W2 -- scalar-accumulator gemm, 3 configs ----
  const float2* W2f = (const float2*)W2;
  float ax0 = 0, ax1 = 0, ax2 = 0;
  float ay0 = 0, ay1 = 0, ay2 = 0;

  for (int h = 0; h < 128; h += 4) {
    float4 q0 = *(const float4*)(y1p + 0 * 128 + h);  // wave-broadcast LDS
    float4 q1 = *(const float4*)(y1p + 1 * 128 + h);
    float4 q2 = *(const float4*)(y1p + 2 * 128 + h);
    #pragma unroll
    for (int j = 0; j < 4; ++j) {
      float2 wf = W2f[(h + j) * 64 + o2];
      float w0 = wf.x, w1 = wf.y, y;
      y = COMP4(q0, j); ax0 += y * w0; ay0 += y * w1;
      y = COMP4(q1, j); ax1 += y * w0; ay1 += y * w1;
      y = COMP4(q2, j); ax2 += y * w0; ay2 += y * w1;
    }
  }

  float2* tab = (float2*)(ws + WS_TAB);
  if (cfg0 + 0 < NCFG) tab[(cfg0 + 0) * 64 + o2] = make_float2(ax0, ay0);
  if (cfg0 + 1 < NCFG) tab[(cfg0 + 1) * 64 + o2] = make_float2(ax1, ay1);
  if (cfg0 + 2 < NCFG) tab[(cfg0 + 2) * 64 + o2] = make_float2(ax2, ay2);
}

__global__ __launch_bounds__(256) void gather_kernel(
    const int* __restrict__ archs, const float* __restrict__ ws,
    float* __restrict__ out)
{
  const int t  = threadIdx.x;
  const int pp = t >> 6;
  const int o2 = t & 63;
  const int P  = blockIdx.x * 4 + pp;
  const int c  = P & 1;

  __shared__ int archsh[64];
  if (t < 64) archsh[t] = archs[blockIdx.x * 64 + t];
  __syncthreads();

  int f[8], op[8];
  #pragma unroll
  for (int e = 0; e < 8; ++e) { f[e] = archsh[pp * 16 + e]; op[e] = archsh[pp * 16 + 8 + e]; }

  const float2* tab = (const float2*)(ws + WS_TAB);
  const float2* a2f = (const float2*)(ws + WS_AT2F);

  float2 S0 = tab[(NCFG_REAL + c * 2 + 0) * 64 + o2];
  float2 S1 = tab[(NCFG_REAL + c * 2 + 1) * 64 + o2];
  float2 S2, S3, S4, S5;
  {
    const int ib[4] = {0, 196, 637, 1421};
    #pragma unroll
    for (int i = 2; i < 6; ++i) {
      int e0 = 2 * (i - 2), e1 = e0 + 1;
      int cid = c * CPER + ib[i - 2] +
                ((f[e0] * 7 + op[e0]) * i + f[e1]) * 7 + op[e1];
      float2 v = tab[cid * 64 + o2];
      if (i == 2) S2 = v; else if (i == 3) S3 = v;
      else if (i == 4) S4 = v; else S5 = v;
    }
  }
  float2 A2[8];
  #pragma unroll
  for (int e = 0; e < 8; ++e) A2[e] = a2f[op[e] * 64 + o2];

  float r0 = S2.x + S3.x + S4.x + S5.x;
  float r1 = S2.y + S3.y + S4.y + S5.y;
  #pragma unroll
  for (int e = 0; e < 8; ++e) {
    int fe = f[e];
    float sx, sy;
    if (fe == 0)      { sx = S0.x; sy = S0.y; }
    else if (fe == 1) { sx = S1.x; sy = S1.y; }
    else if (fe == 2) { sx = S2.x; sy = S2.y; }
    else if (fe == 3) { sx = S3.x; sy = S3.y; }
    else              { sx = S4.x; sy = S4.y; }
    r0 += A2[e].x * sx;
    r1 += A2[e].y * sy;
  }
  ((float2*)out)[P * 64 + o2] = make_float2(r0 * 0.25f, r1 * 0.25f);
}

// ===================== FALLBACK: R9 verbatim (if ws too small) ============
#define FB_S1   0
#define FB_AT1  1536
#define FB_AT2  2432
#define FB_S2I  3328

__global__ __launch_bounds__(512) void precompute_kernel(
    const float* __restrict__ init_emb, const float* __restrict__ other_emb,
    const float* __restrict__ op_embs,  const float* __restrict__ Wx,
    const float* __restrict__ bx,       const float* __restrict__ W1,
    const float* __restrict__ Wa1,      const float* __restrict__ ba1,
    const float* __restrict__ W2,       const float* __restrict__ Wa2,
    const float* __restrict__ ba2,      float* __restrict__ ws)
{
  const int t   = threadIdx.x;
  const int blk = blockIdx.x;
  __shared__ float y0[576];
  __shared__ float s1sh[1536];
  for (int idx = t; idx < 576; idx += 512) {
    int c = idx / 288, i = (idx / 48) % 6, h = idx % 48;
    const float* nptr = (i < 2) ? (init_emb + (c * 2 + i) * 48)
                                : (other_emb + c * 48);
    float acc = bx[h];
    for (int d = 0; d < 48; ++d) acc += nptr[d] * Wx[d * 48 + h];
    y0[idx] = acc;
  }
  __syncthreads();
  for (int idx = t; idx < 1536; idx += 512) {
    int ci = idx >> 7, o = idx & 127;
    const float* yp = y0 + ci * 48;
    float acc = 0.f;
    for (int h = 0; h < 48; ++h) acc += yp[h] * W1[h * 128 + o];
    s1sh[idx] = acc;
    ws[FB_S1 + idx] = acc;
  }
  for (int idx = blk * 112 + t; idx < (blk + 1) * 112; idx += 512) {
    int op = idx >> 7, o = idx & 127;
    float a1 = ba1[o], a2 = ba2[o];
    for (int d = 0; d < 48; ++d) {
      float e = op_embs[op * 48 + d];
      a1 += e * Wa1[d * 128 + o];
      a2 += e * Wa2[d * 128 + o];
    }
    ws[FB_AT1 + idx] = (op == 0) ? 0.f : sigmoidf_(a1);
    ws[FB_AT2 + idx] = (op == 0) ? 0.f : sigmoidf_(a2);
  }
  __syncthreads();
  for (int idx = blk * 64 + t; idx < (blk + 1) * 64; idx += 512) {
    int c = idx >> 8, i = (idx >> 7) & 1, o = idx & 127;
    const float* sp = s1sh + (c * 6 + i) * 128;
    float acc = 0.f;
    for (int h = 0; h < 128; ++h) acc += fmaxf(sp[h], 0.f) * W2[h * 128 + o];
    ws[FB_S2I + idx] = acc;
  }
}

__global__ __launch_bounds__(256) void main_kernel(
    const int* __restrict__ archs, const float* __restrict__ W2,
    const float* __restrict__ ws, float* __restrict__ out)
{
  const int t  = threadIdx.x;
  const int pp = t >> 6;
  const int o2 = t & 63;
  const int P  = blockIdx.x * 4 + pp;
  const int c  = P & 1;
  __shared__ float y1sh[4][512];
  __shared__ int   archsh[64];
  if (t < 64) archsh[t] = archs[blockIdx.x * 64 + t];
  __syncthreads();
  int f[8], op[8];
  #pragma unroll
  for (int e = 0; e < 8; ++e) { f[e] = archsh[pp * 16 + e]; op[e] = archsh[pp * 16 + 8 + e]; }
  const float2* s1p = (const float2*)ws + c * 384;
  const float2* at1 = (const float2*)(ws + FB_AT1);
  const float2* at2 = (const float2*)(ws + FB_AT2);
  const float2* s2i = (const float2*)(ws + FB_S2I) + c * 128;
  float2 A2[8];
  #pragma unroll
  for (int e = 0; e < 8; ++e) A2[e] = at2[op[e] * 64 + o2];
  float2 S0 = s2i[o2], S1 = s2i[64 + o2];
  #pragma unroll
  for (int i = 0; i < 4; ++i) {
    float2 v = s1p[(2 + i) * 64 + o2];
    int e0 = 2 * i, e1 = 2 * i + 1;
    float2 A0 = at1[op[e0] * 64 + o2];
    float2 B0 = s1p[f[e0] * 64 + o2];
    float2 A1 = at1[op[e1] * 64 + o2];
    float2 B1 = s1p[f[e1] * 64 + o2];
    v.x += A0.x * B0.x + A1.x * B1.x;
    v.y += A0.y * B0.y + A1.y * B1.y;
    ((float2*)(y1sh[pp] + i * 128))[o2] =
        make_float2(fmaxf(v.x, 0.f), fmaxf(v.y, 0.f));
  }
  __syncthreads();
  const float* y1p = y1sh[pp];
  const float2* W2f = (const float2*)W2;
  float ax0 = 0, ax1 = 0, ax2 = 0, ax3 = 0;
  float ay0 = 0, ay1 = 0, ay2 = 0, ay3 = 0;
  for (int h = 0; h < 128; h += 4) {
    float4 q0 = *(const float4*)(y1p + 0 * 128 + h);
    float4 q1 = *(const float4*)(y1p + 1 * 128 + h);
    float4 q2 = *(const float4*)(y1p + 2 * 128 + h);
    float4 q3 = *(const float4*)(y1p + 3 * 128 + h);
    #pragma unroll
    for (int j = 0; j < 4; ++j) {
      float2 wf = W2f[(h + j) * 64 + o2];
      float w0 = wf.x, w1 = wf.y, y;
      y = COMP4(q0, j); ax0 += y * w0; ay0 += y * w1;
      y = COMP4(q1, j); ax1 += y * w0; ay1 += y * w1;
      y = COMP4(q2, j); ax2 += y * w0; ay2 += y * w1;
      y = COMP4(q3, j); ax3 += y * w0; ay3 += y * w1;
    }
  }
  float r0 = ax0 + ax1 + ax2 + ax3;
  float r1 = ay0 + ay1 + ay2 + ay3;
  #pragma unroll
  for (int e = 0; e < 8; ++e) {
    int fe = f[e];
    float sx, sy;
    if (fe == 0)      { sx = S0.x; sy = S0.y; }
    else if (fe == 1) { sx = S1.x; sy = S1.y; }
    else if (fe == 2) { sx = ax0; sy = ay0; }
    else if (fe == 3) { sx = ax1; sy = ay1; }
    else if (fe == 4) { sx = ax2; sy = ay2; }
    else              { sx = ax3; sy = ay3; }
    r0 += A2[e].x * sx;
    r1 += A2[e].y * sy;
  }
  ((float2*)out)[P * 64 + o2] = make_float2(r0 * 0.25f, r1 * 0.25f);
}

extern "C" void kernel_launch(void* const* d_in, const int* in_sizes, int n_in,
                              void* d_out, int out_size, void* d_ws, size_t ws_size,
                              hipStream_t stream) {
  const int* archs = (const int*)d_in[0];
  float* ws = (float*)d_ws;
  if (ws_size >= WS_NEED) {
    config_kernel<<<NBLK, 512, 0, stream>>>(
        (const float*)d_in[1], (const float*)d_in[2], (const float*)d_in[3],
        (const float*)d_in[4], (const float*)d_in[5], (const float*)d_in[6],
        (const float*)d_in[7], (const float*)d_in[8], (const float*)d_in[9],
        (const float*)d_in[10], (const float*)d_in[11], ws);
    gather_kernel<<<NPAIR / 4, 256, 0, stream>>>(archs, ws, (float*)d_out);
  } else {
    precompute_kernel<<<8, 512, 0, stream>>>(
        (const float*)d_in[1], (const float*)d_in[2], (const float*)d_in[3],
        (const float*)d_in[4], (const float*)d_in[5], (const float*)d_in[6],
        (const float*)d_in[7], (const float*)d_in[8], (const float*)d_in[9],
        (const float*)d_in[10], (const float*)d_in[11], ws);
    main_kernel<<<NPAIR / 4, 256, 0, stream>>>(archs, (const float*)d_in[9], ws,
                                               (float*)d_out);
  }
}

// Round 5
// 98.281 us; speedup vs baseline: 2.3980x; 1.0257x over previous
//
#include <hip/hip_runtime.h>

#define NPAIR 8192   // B*NCG

// ===================== config-deduplicated path =====================
// Node layer-1 output depends only on (c, i, f_s0, op_s0, f_s1, op_s1):
// 5292 real configs + 4 init pseudo-rows = 5296. config_kernel builds
// tab[cfg] = relu(y1_cfg) @ W2; gather_kernel is a pure gather/aggregate.
// R14: scalar/compile-time-indexed accumulators only (runtime-indexed
//   register arrays spill to scratch).
// R15: cooperative fusion FAILED (235us). NEVER use cooperative launch here.
// R16 FAILED (127us): narrow strided global loads latency-exposed.
// R17 (104us): stage ALL weights at t0 (one ~86KB burst), fuse s1|at1|at2.
// R18 (100.8us): 512 thr. Forensics: step 3 issued 2 scalar ds_read_b32 per
//   FMA = 1.28MB LDS traffic/block; LDS BW is PER-CU, so extra waves don't
//   help -- the phase is LDS-BANDWIDTH-bound (~12us of ~15us config).
// R19: 2-D register blocking + b128 LDS reads. s1 thread = (2 ci x 4 o)
//   tile (W reused over ci, y over o); at1/at2 thread = (3 op x 4 o);
//   op-0 rows written as zeros (analytically zero), never computed.
//   Step-3 LDS instrs ~13x down. Step 2 same treatment (144 thr, all-b128).
#define NCFG_REAL 5292
#define NCFG      5296
#define CPER      2646
#define NBLK      221       // <= 256: single wave of blocks, no tail round
#define WS_AT2F   0         // at2 table [7][128] (row 0 zeroed)
#define WS_TAB    1024      // tab [NCFG][128]
#define WS_NEED   ((size_t)(1024 + NCFG * 128) * 4)

#define COMP4(v, j) ((j) == 0 ? (v).x : (j) == 1 ? (v).y : (j) == 2 ? (v).z : (v).w)

__device__ __forceinline__ float sigmoidf_(float x) {
  return 1.0f / (1.0f + __expf(-x));
}

// 221 blocks x 512 threads; 24 configs per block, 3 per wave.
__global__ __launch_bounds__(512) void config_kernel(
    const float* __restrict__ init_emb, const float* __restrict__ other_emb,
    const float* __restrict__ op_embs,  const float* __restrict__ Wx,
    const float* __restrict__ bx,       const float* __restrict__ W1,
    const float* __restrict__ Wa1,      const float* __restrict__ ba1,
    const float* __restrict__ W2,       const float* __restrict__ Wa2,
    const float* __restrict__ ba2,      float* __restrict__ ws)
{
  __shared__ __align__(16) float wx_sh[2304];   // Wx 48x48
  __shared__ __align__(16) float w1_sh[6144];   // W1 48x128
  __shared__ __align__(16) float wa1sh[6144];   // Wa1 48x128; later y1 overlay
  __shared__ __align__(16) float wa2sh[6144];   // Wa2 48x128
  __shared__ __align__(16) float s1sh[1536];    // support1 [2][6][128]
  __shared__ __align__(16) float at1sh[896];    // sigmoid(a1) [7][128] row0=0
  __shared__ __align__(16) float at2sh[896];    // sigmoid(a2) [7][128] row0=0
  __shared__ __align__(16) float y0sh[576];     // y0 [2][6][48]
  __shared__ __align__(16) float embsh[336];    // init(192) other(96) bx(48)
  __shared__ __align__(16) float opsh[336];     // op_embs [7][48]
  const int t = threadIdx.x;

  // ---- step 1: stage EVERYTHING (one wide burst, single wait) ----
  for (int i = t; i < 576; i += 512)  ((float4*)wx_sh)[i] = ((const float4*)Wx)[i];
  for (int i = t; i < 1536; i += 512) ((float4*)w1_sh)[i] = ((const float4*)W1)[i];
  for (int i = t; i < 1536; i += 512) ((float4*)wa1sh)[i] = ((const float4*)Wa1)[i];
  for (int i = t; i < 1536; i += 512) ((float4*)wa2sh)[i] = ((const float4*)Wa2)[i];
  if (t < 48)        ((float4*)embsh)[t]     = ((const float4*)init_emb)[t];
  else if (t < 72)   ((float4*)embsh)[t]     = ((const float4*)other_emb)[t - 48];
  else if (t < 84)   ((float4*)embsh)[t]     = ((const float4*)bx)[t - 72];
  else if (t < 168)  ((float4*)opsh)[t - 84] = ((const float4*)op_embs)[t - 84];
  __syncthreads();

  // ---- step 2: y0[r][h] = node @ Wx + bx, all-b128 LDS reads ----
  // 144 threads: r = t/12 (row 0..11), h4 = t%12 (float4 along h).
  if (t < 144) {
    const int r = t / 12, h4 = t - r * 12;
    const int c = r / 6, i = r - c * 6;
    const float* nptr = (i < 2) ? (embsh + (c * 2 + i) * 48)
                                : (embsh + 192 + c * 48);
    float4 acc = *(const float4*)(embsh + 288 + h4 * 4);   // bx
    #pragma unroll
    for (int d4 = 0; d4 < 12; ++d4) {
      float4 nv = *(const float4*)(nptr + d4 * 4);
      #pragma unroll
      for (int j = 0; j < 4; ++j) {
        float4 wv = *(const float4*)(wx_sh + (d4 * 4 + j) * 48 + h4 * 4);
        float s = COMP4(nv, j);
        acc.x += s * wv.x; acc.y += s * wv.y;
        acc.z += s * wv.z; acc.w += s * wv.w;
      }
    }
    *(float4*)(y0sh + r * 48 + h4 * 4) = acc;
  }
  __syncthreads();

  // ---- step 3: register-blocked s1 | at1 | at2 (all-b128 LDS reads) ----
  // Role by wave-aligned tid range: [0,192) s1, [192,256) at1, [256,320) at2,
  // [320,448) zero op-0 rows. W values reused across ci/op rows in registers.
  if (t < 192) {
    // s1: thread = (2 ci) x (4 o) tile. ci2 = t>>5 in [0,6), o4 = (t&31)*4.
    const int ci2 = t >> 5, o4 = (t & 31) << 2;
    const float* yA = y0sh + (2 * ci2) * 48;
    const float* yB = yA + 48;
    float4 a0 = make_float4(0.f, 0.f, 0.f, 0.f);
    float4 a1 = make_float4(0.f, 0.f, 0.f, 0.f);
    #pragma unroll
    for (int h4 = 0; h4 < 12; ++h4) {
      float4 ya = *(const float4*)(yA + h4 * 4);
      float4 yb = *(const float4*)(yB + h4 * 4);
      #pragma unroll
      for (int j = 0; j < 4; ++j) {
        float4 wv = *(const float4*)(w1_sh + (h4 * 4 + j) * 128 + o4);
        float sa = COMP4(ya, j), sb = COMP4(yb, j);
        a0.x += sa * wv.x; a0.y += sa * wv.y; a0.z += sa * wv.z; a0.w += sa * wv.w;
        a1.x += sb * wv.x; a1.y += sb * wv.y; a1.z += sb * wv.z; a1.w += sb * wv.w;
      }
    }
    *(float4*)(s1sh + (2 * ci2) * 128 + o4)     = a0;
    *(float4*)(s1sh + (2 * ci2 + 1) * 128 + o4) = a1;
  } else if (t < 320) {
    // at1/at2: thread = (3 op) x (4 o). ops {1,2,3} or {4,5,6}; op0 zeroed below.
    const int is2  = (t >= 256);
    const int u    = t - (is2 ? 256 : 192);
    const int half = u >> 5, o4 = (u & 31) << 2;
    const int op0_ = 1 + 3 * half;
    const float* wsh_  = is2 ? wa2sh : wa1sh;
    const float* bias  = is2 ? ba2 : ba1;
    float*       outsh = is2 ? at2sh : at1sh;
    float4 bv = *(const float4*)(bias + o4);
    float4 b0 = bv, b1 = bv, b2 = bv;
    const float* e0p = opsh + (op0_ + 0) * 48;
    const float* e1p = opsh + (op0_ + 1) * 48;
    const float* e2p = opsh + (op0_ + 2) * 48;
    #pragma unroll
    for (int h4 = 0; h4 < 12; ++h4) {
      float4 e0 = *(const float4*)(e0p + h4 * 4);
      float4 e1 = *(const float4*)(e1p + h4 * 4);
      float4 e2 = *(const float4*)(e2p + h4 * 4);
      #pragma unroll
      for (int j = 0; j < 4; ++j) {
        float4 wv = *(const float4*)(wsh_ + (h4 * 4 + j) * 128 + o4);
        float s0 = COMP4(e0, j), s1_ = COMP4(e1, j), s2 = COMP4(e2, j);
        b0.x += s0 * wv.x; b0.y += s0 * wv.y; b0.z += s0 * wv.z; b0.w += s0 * wv.w;
        b1.x += s1_ * wv.x; b1.y += s1_ * wv.y; b1.z += s1_ * wv.z; b1.w += s1_ * wv.w;
        b2.x += s2 * wv.x; b2.y += s2 * wv.y; b2.z += s2 * wv.z; b2.w += s2 * wv.w;
      }
    }
    b0 = make_float4(sigmoidf_(b0.x), sigmoidf_(b0.y), sigmoidf_(b0.z), sigmoidf_(b0.w));
    b1 = make_float4(sigmoidf_(b1.x), sigmoidf_(b1.y), sigmoidf_(b1.z), sigmoidf_(b1.w));
    b2 = make_float4(sigmoidf_(b2.x), sigmoidf_(b2.y), sigmoidf_(b2.z), sigmoidf_(b2.w));
    *(float4*)(outsh + (op0_ + 0) * 128 + o4) = b0;
    *(float4*)(outsh + (op0_ + 1) * 128 + o4) = b1;
    *(float4*)(outsh + (op0_ + 2) * 128 + o4) = b2;
    if (is2 && blockIdx.x == 0) {   // publish at2 once (gather reads it)
      *(float4*)(ws + WS_AT2F + (op0_ + 0) * 128 + o4) = b0;
      *(float4*)(ws + WS_AT2F + (op0_ + 1) * 128 + o4) = b1;
      *(float4*)(ws + WS_AT2F + (op0_ + 2) * 128 + o4) = b2;
    }
  } else if (t < 448) {
    // zero op-0 rows (op==NONE is masked to exactly 0)
    const int u = t - 320;   // 0..127
    at1sh[u] = 0.f;
    at2sh[u] = 0.f;
    if (blockIdx.x == 0) ws[WS_AT2F + u] = 0.f;
  }
  __syncthreads();                    // wa1sh readers done -> y1 overlay ok

  // ---- step 6: wave w -> 3 configs, y1 rows into wa1sh[w*384 ..] ----
  const int w  = t >> 6, o2 = t & 63;          // w in [0,8)
  const int cfg0 = blockIdx.x * 24 + w * 3;    // up to 5303; tail guarded
  const float2* s1f = (const float2*)s1sh;     // [12][64]
  const float2* a1f = (const float2*)at1sh;    // [7][64]
  float* y1p = wa1sh + w * 384;                // [3 configs][128]

  #pragma unroll
  for (int r = 0; r < 3; ++r) {
    int cfg = cfg0 + r;
    float2 v;
    if (cfg < NCFG_REAL) {
      int c = cfg / CPER, q = cfg % CPER;
      int i, b;
      if (q < 196)       { i = 2; b = 0; }
      else if (q < 637)  { i = 3; b = 196; }
      else if (q < 1421) { i = 4; b = 637; }
      else               { i = 5; b = 1421; }
      q -= b;
      int op2_ = q % 7; q /= 7;
      int f2_  = q % i; q /= i;
      int op1_ = q % 7;
      int f1_  = q / 7;
      int cb = c * 384;
      v = s1f[cb + i * 64 + o2];
      float2 A0 = a1f[op1_ * 64 + o2], B0 = s1f[cb + f1_ * 64 + o2];
      float2 A1 = a1f[op2_ * 64 + o2], B1 = s1f[cb + f2_ * 64 + o2];
      v.x += A0.x * B0.x + A1.x * B1.x;
      v.y += A0.y * B0.y + A1.y * B1.y;
    } else if (cfg < NCFG) {           // init node pseudo-config (no in-edges)
      int j = cfg - NCFG_REAL, c = j >> 1, i = j & 1;
      v = s1f[c * 384 + i * 64 + o2];
    } else {                           // tail slot (block 220 only)
      v = make_float2(0.f, 0.f);
    }
    ((float2*)(y1p + r * 128))[o2] =
        make_float2(fmaxf(v.x, 0.f), fmaxf(v.y, 0.f));
  }
  __syncthreads();

  // ---- step 7: tab rows = y1 @ W2 -- scalar-accumulator gemm, 3 configs ----
  const float2* W2f = (const float2*)W2;
  float ax0 = 0, ax1 = 0, ax2 = 0;
  float ay0 = 0, ay1 = 0, ay2 = 0;

  for (int h = 0; h < 128; h += 4) {
    float4 q0 = *(const float4*)(y1p + 0 * 128 + h);  // wave-broadcast LDS
    float4 q1 = *(const float4*)(y1p + 1 * 128 + h);
    float4 q2 = *(const float4*)(y1p + 2 * 128 + h);
    #pragma unroll
    for (int j = 0; j < 4; ++j) {
      float2 wf = W2f[(h + j) * 64 + o2];
      float w0 = wf.x, w1 = wf.y, y;
      y = COMP4(q0, j); ax0 += y * w0; ay0 += y * w1;
      y = COMP4(q1, j); ax1 += y * w0; ay1 += y * w1;
      y = COMP4(q2, j); ax2 += y * w0; ay2 += y * w1;
    }
  }

  float2* tab = (float2*)(ws + WS_TAB);
  if (cfg0 + 0 < NCFG) tab[(cfg0 + 0) * 64 + o2] = make_float2(ax0, ay0);
  if (cfg0 + 1 < NCFG) tab[(cfg0 + 1) * 64 + o2] = make_float2(ax1, ay1);
  if (cfg0 + 2 < NCFG) tab[(cfg0 + 2) * 64 + o2] = make_float2(ax2, ay2);
}

__global__ __launch_bounds__(256) void gather_kernel(
    const int* __restrict__ archs, const float* __restrict__ ws,
    float* __restrict__ out)
{
  const int t  = threadIdx.x;
  const int pp = t >> 6;
  const int o2 = t & 63;
  const int P  = blockIdx.x * 4 + pp;
  const int c  = P & 1;

  __shared__ int archsh[64];
  if (t < 64) archsh[t] = archs[blockIdx.x * 64 + t];
  __syncthreads();

  int f[8], op[8];
  #pragma unroll
  for (int e = 0; e < 8; ++e) { f[e] = archsh[pp * 16 + e]; op[e] = archsh[pp * 16 + 8 + e]; }

  const float2* tab = (const float2*)(ws + WS_TAB);
  const float2* a2f = (const float2*)(ws + WS_AT2F);

  float2 S0 = tab[(NCFG_REAL + c * 2 + 0) * 64 + o2];
  float2 S1 = tab[(NCFG_REAL + c * 2 + 1) * 64 + o2];
  float2 S2, S3, S4, S5;
  {
    const int ib[4] = {0, 196, 637, 1421};
    #pragma unroll
    for (int i = 2; i < 6; ++i) {
      int e0 = 2 * (i - 2), e1 = e0 + 1;
      int cid = c * CPER + ib[i - 2] +
                ((f[e0] * 7 + op[e0]) * i + f[e1]) * 7 + op[e1];
      float2 v = tab[cid * 64 + o2];
      if (i == 2) S2 = v; else if (i == 3) S3 = v;
      else if (i == 4) S4 = v; else S5 = v;
    }
  }
  float2 A2[8];
  #pragma unroll
  for (int e = 0; e < 8; ++e) A2[e] = a2f[op[e] * 64 + o2];

  float r0 = S2.x + S3.x + S4.x + S5.x;
  float r1 = S2.y + S3.y + S4.y + S5.y;
  #pragma unroll
  for (int e = 0; e < 8; ++e) {
    int fe = f[e];
    float sx, sy;
    if (fe == 0)      { sx = S0.x; sy = S0.y; }
    else if (fe == 1) { sx = S1.x; sy = S1.y; }
    else if (fe == 2) { sx = S2.x; sy = S2.y; }
    else if (fe == 3) { sx = S3.x; sy = S3.y; }
    else              { sx = S4.x; sy = S4.y; }
    r0 += A2[e].x * sx;
    r1 += A2[e].y * sy;
  }
  ((float2*)out)[P * 64 + o2] = make_float2(r0 * 0.25f, r1 * 0.25f);
}

// ===================== FALLBACK: R9 verbatim (if ws too small) ============
#define FB_S1   0
#define FB_AT1  1536
#define FB_AT2  2432
#define FB_S2I  3328

__global__ __launch_bounds__(512) void precompute_kernel(
    const float* __restrict__ init_emb, const float* __restrict__ other_emb,
    const float* __restrict__ op_embs,  const float* __restrict__ Wx,
    const float* __restrict__ bx,       const float* __restrict__ W1,
    const float* __restrict__ Wa1,      const float* __restrict__ ba1,
    const float* __restrict__ W2,       const float* __restrict__ Wa2,
    const float* __restrict__ ba2,      float* __restrict__ ws)
{
  const int t   = threadIdx.x;
  const int blk = blockIdx.x;
  __shared__ float y0[576];
  __shared__ float s1sh[1536];
  for (int idx = t; idx < 576; idx += 512) {
    int c = idx / 288, i = (idx / 48) % 6, h = idx % 48;
    const float* nptr = (i < 2) ? (init_emb + (c * 2 + i) * 48)
                                : (other_emb + c * 48);
    float acc = bx[h];
    for (int d = 0; d < 48; ++d) acc += nptr[d] * Wx[d * 48 + h];
    y0[idx] = acc;
  }
  __syncthreads();
  for (int idx = t; idx < 1536; idx += 512) {
    int ci = idx >> 7, o = idx & 127;
    const float* yp = y0 + ci * 48;
    float acc = 0.f;
    for (int h = 0; h < 48; ++h) acc += yp[h] * W1[h * 128 + o];
    s1sh[idx] = acc;
    ws[FB_S1 + idx] = acc;
  }
  for (int idx = blk * 112 + t; idx < (blk + 1) * 112; idx += 512) {
    int op = idx >> 7, o = idx & 127;
    float a1 = ba1[o], a2 = ba2[o];
    for (int d = 0; d < 48; ++d) {
      float e = op_embs[op * 48 + d];
      a1 += e * Wa1[d * 128 + o];
      a2 += e * Wa2[d * 128 + o];
    }
    ws[FB_AT1 + idx] = (op == 0) ? 0.f : sigmoidf_(a1);
    ws[FB_AT2 + idx] = (op == 0) ? 0.f : sigmoidf_(a2);
  }
  __syncthreads();
  for (int idx = blk * 64 + t; idx < (blk + 1) * 64; idx += 512) {
    int c = idx >> 8, i = (idx >> 7) & 1, o = idx & 127;
    const float* sp = s1sh + (c * 6 + i) * 128;
    float acc = 0.f;
    for (int h = 0; h < 128; ++h) acc += fmaxf(sp[h], 0.f) * W2[h * 128 + o];
    ws[FB_S2I + idx] = acc;
  }
}

__global__ __launch_bounds__(256) void main_kernel(
    const int* __restrict__ archs, const float* __restrict__ W2,
    const float* __restrict__ ws, float* __restrict__ out)
{
  const int t  = threadIdx.x;
  const int pp = t >> 6;
  const int o2 = t & 63;
  const int P  = blockIdx.x * 4 + pp;
  const int c  = P & 1;
  __shared__ float y1sh[4][512];
  __shared__ int   archsh[64];
  if (t < 64) archsh[t] = archs[blockIdx.x * 64 + t];
  __syncthreads();
  int f[8], op[8];
  #pragma unroll
  for (int e = 0; e < 8; ++e) { f[e] = archsh[pp * 16 + e]; op[e] = archsh[pp * 16 + 8 + e]; }
  const float2* s1p = (const float2*)ws + c * 384;
  const float2* at1 = (const float2*)(ws + FB_AT1);
  const float2* at2 = (const float2*)(ws + FB_AT2);
  const float2* s2i = (const float2*)(ws + FB_S2I) + c * 128;
  float2 A2[8];
  #pragma unroll
  for (int e = 0; e < 8; ++e) A2[e] = at2[op[e] * 64 + o2];
  float2 S0 = s2i[o2], S1 = s2i[64 + o2];
  #pragma unroll
  for (int i = 0; i < 4; ++i) {
    float2 v = s1p[(2 + i) * 64 + o2];
    int e0 = 2 * i, e1 = 2 * i + 1;
    float2 A0 = at1[op[e0] * 64 + o2];
    float2 B0 = s1p[f[e0] * 64 + o2];
    float2 A1 = at1[op[e1] * 64 + o2];
    float2 B1 = s1p[f[e1] * 64 + o2];
    v.x += A0.x * B0.x + A1.x * B1.x;
    v.y += A0.y * B0.y + A1.y * B1.y;
    ((float2*)(y1sh[pp] + i * 128))[o2] =
        make_float2(fmaxf(v.x, 0.f), fmaxf(v.y, 0.f));
  }
  __syncthreads();
  const float* y1p = y1sh[pp];
  const float2* W2f = (const float2*)W2;
  float ax0 = 0, ax1 = 0, ax2 = 0, ax3 = 0;
  float ay0 = 0, ay1 = 0, ay2 = 0, ay3 = 0;
  for (int h = 0; h < 128; h += 4) {
    float4 q0 = *(const float4*)(y1p + 0 * 128 + h);
    float4 q1 = *(const float4*)(y1p + 1 * 128 + h);
    float4 q2 = *(const float4*)(y1p + 2 * 128 + h);
    float4 q3 = *(const float4*)(y1p + 3 * 128 + h);
    #pragma unroll
    for (int j = 0; j < 4; ++j) {
      float2 wf = W2f[(h + j) * 64 + o2];
      float w0 = wf.x, w1 = wf.y, y;
      y = COMP4(q0, j); ax0 += y * w0; ay0 += y * w1;
      y = COMP4(q1, j); ax1 += y * w0; ay1 += y * w1;
      y = COMP4(q2, j); ax2 += y * w0; ay2 += y * w1;
      y = COMP4(q3, j); ax3 += y * w0; ay3 += y * w1;
    }
  }
  float r0 = ax0 + ax1 + ax2 + ax3;
  float r1 = ay0 + ay1 + ay2 + ay3;
  #pragma unroll
  for (int e = 0; e < 8; ++e) {
    int fe = f[e];
    float sx, sy;
    if (fe == 0)      { sx = S0.x; sy = S0.y; }
    else if (fe == 1) { sx = S1.x; sy = S1.y; }
    else if (fe == 2) { sx = ax0; sy = ay0; }
    else if (fe == 3) { sx = ax1; sy = ay1; }
    else if (fe == 4) { sx = ax2; sy = ay2; }
    else              { sx = ax3; sy = ay3; }
    r0 += A2[e].x * sx;
    r1 += A2[e].y * sy;
  }
  ((float2*)out)[P * 64 + o2] = make_float2(r0 * 0.25f, r1 * 0.25f);
}

extern "C" void kernel_launch(void* const* d_in, const int* in_sizes, int n_in,
                              void* d_out, int out_size, void* d_ws, size_t ws_size,
                              hipStream_t stream) {
  const int* archs = (const int*)d_in[0];
  float* ws = (float*)d_ws;
  if (ws_size >= WS_NEED) {
    config_kernel<<<NBLK, 512, 0, stream>>>(
        (const float*)d_in[1], (const float*)d_in[2], (const float*)d_in[3],
        (const float*)d_in[4], (const float*)d_in[5], (const float*)d_in[6],
        (const float*)d_in[7], (const float*)d_in[8], (const float*)d_in[9],
        (const float*)d_in[10], (const float*)d_in[11], ws);
    gather_kernel<<<NPAIR / 4, 256, 0, stream>>>(archs, ws, (float*)d_out);
  } else {
    precompute_kernel<<<8, 512, 0, stream>>>(
        (const float*)d_in[1], (const float*)d_in[2], (const float*)d_in[3],
        (const float*)d_in[4], (const float*)d_in[5], (const float*)d_in[6],
        (const float*)d_in[7], (const float*)d_in[8], (const float*)d_in[9],
        (const float*)d_in[10], (const float*)d_in[11], ws);
    main_kernel<<<NPAIR / 4, 256, 0, stream>>>(archs, (const float*)d_in[9], ws,
                                               (float*)d_out);
  }
}